// Round 4
// baseline (683.218 us; speedup 1.0000x reference)
//
#include <hip/hip_runtime.h>
#include <math.h>

#define N_NODES 50000
#define N_EDGES 800000
#define HEADS 4
#define N_GRAPHS 64
#define NEG_SLOPE 0.2f

// monotone float<->uint key for atomicMax-based segment max (pooling).
// key==0 is smaller than key(x) for any finite float x.
__device__ __forceinline__ unsigned fkey(float f) {
    unsigned u = __float_as_uint(f);
    return (u & 0x80000000u) ? ~u : (u | 0x80000000u);
}
__device__ __forceinline__ float kval(unsigned k) {
    unsigned u = (k & 0x80000000u) ? (k & 0x7FFFFFFFu) : ~k;
    return __uint_as_float(u);
}

// ---------------- CSR build (counting sort by dst) ----------------

__global__ void hist_kernel(const int* __restrict__ dst, int* __restrict__ deg) {
    int e = blockIdx.x * 256 + threadIdx.x;
    if (e < N_EDGES) atomicAdd(&deg[dst[e]], 1);
}

// single-block single-pass scan: 1024 threads x 49-element serial chunks,
// wave shuffle-scan + 16-entry LDS scan of wave totals. 2 barriers total.
__global__ void scan_kernel(const int* __restrict__ deg, int* __restrict__ row_start,
                            int* __restrict__ cursor) {
    __shared__ int wsum[16];
    int t = threadIdx.x;          // 1024
    int base = t * 49;            // 1024*49 = 50176 >= N_NODES
    int s = 0;
    for (int i = 0; i < 49; ++i) {
        int idx = base + i;
        s += (idx < N_NODES) ? deg[idx] : 0;
    }
    int lane = t & 63, wid = t >> 6;
    // inclusive shuffle scan within wave
    int v = s;
    #pragma unroll
    for (int off = 1; off < 64; off <<= 1) {
        int u = __shfl_up(v, off, 64);
        if (lane >= off) v += u;
    }
    if (lane == 63) wsum[wid] = v;
    __syncthreads();
    if (wid == 0 && lane < 16) {
        int wv = wsum[lane];
        #pragma unroll
        for (int off = 1; off < 16; off <<= 1) {
            int u = __shfl_up(wv, off, 64);
            if (lane >= off) wv += u;
        }
        wsum[lane] = wv;          // inclusive wave-total prefix
    }
    __syncthreads();
    int waveoff = (wid == 0) ? 0 : wsum[wid - 1];
    int run = waveoff + v - s;    // exclusive prefix of this thread's chunk
    for (int i = 0; i < 49; ++i) {
        int idx = base + i;
        if (idx < N_NODES) {
            row_start[idx] = run;
            cursor[idx] = run;
            run += deg[idx];
        }
    }
    if (t == 1023) row_start[N_NODES] = run;   // == N_EDGES
}

__global__ void scatter_kernel(const int* __restrict__ src, const int* __restrict__ dst,
                               int* __restrict__ cursor, int* __restrict__ csr_src) {
    int e = blockIdx.x * 256 + threadIdx.x;
    if (e < N_EDGES) {
        int p = atomicAdd(&cursor[dst[e]], 1);
        csr_src[p] = src[e];
    }
}

// ---------------- node pipeline ----------------

// h0[n,:] = embeds[word_ids[n],:]  (float4; 32 float4 per row)
__global__ void gather_kernel(const int* __restrict__ wid, const float4* __restrict__ emb4,
                              float4* __restrict__ h4) {
    int i = blockIdx.x * 256 + threadIdx.x;   // N*32 threads exactly
    int n = i >> 5, q = i & 31;
    h4[i] = emb4[wid[n] * 32 + q];
}

// feat = h @ W (128x128) with W staged in LDS; el/er head dots fused.
// 256 threads, 16 nodes per block, grid = 3125.
__global__ void feat_kernel(const float* __restrict__ h, const float* __restrict__ W,
                            const float* __restrict__ al, const float* __restrict__ ar,
                            float* __restrict__ feat, float* __restrict__ el,
                            float* __restrict__ er) {
    __shared__ float Wl[128 * 128];      // 64 KB
    __shared__ float hl[16][128];        // 8 KB
    int t = threadIdx.x;
    {   // stage W: 4096 float4 / 256 threads = 16 each
        const float4* W4 = (const float4*)W;
        float4* Wl4 = (float4*)Wl;
        #pragma unroll
        for (int i = 0; i < 16; ++i) Wl4[t + 256 * i] = W4[t + 256 * i];
    }
    int n0 = blockIdx.x * 16;
    {   // stage h tile: 512 float4 / 256 threads = 2 each
        const float4* h4 = (const float4*)(h + (size_t)n0 * 128);
        float4* hl4 = (float4*)hl;
        hl4[t] = h4[t];
        hl4[t + 256] = h4[t + 256];
    }
    __syncthreads();
    int cg = (t & 31) * 4;       // channel group (4 consecutive channels)
    int nl = t >> 5;             // local node 0..7
    int hd = (t & 31) >> 3;      // head of this channel group
    float al0 = al[cg], al1 = al[cg + 1], al2 = al[cg + 2], al3 = al[cg + 3];
    float ar0 = ar[cg], ar1 = ar[cg + 1], ar2 = ar[cg + 2], ar3 = ar[cg + 3];
    #pragma unroll
    for (int rep = 0; rep < 2; ++rep) {
        int n = nl + 8 * rep;
        float4 acc = {0.f, 0.f, 0.f, 0.f};
        #pragma unroll 16
        for (int k = 0; k < 128; ++k) {
            float hv = hl[n][k];
            float4 w4 = *(const float4*)&Wl[k * 128 + cg];
            acc.x += hv * w4.x; acc.y += hv * w4.y;
            acc.z += hv * w4.z; acc.w += hv * w4.w;
        }
        *(float4*)(feat + (size_t)(n0 + n) * 128 + cg) = acc;
        float pl = acc.x * al0 + acc.y * al1 + acc.z * al2 + acc.w * al3;
        float pr = acc.x * ar0 + acc.y * ar1 + acc.z * ar2 + acc.w * ar3;
        // reduce over the 8 threads covering one head (contiguous lanes, same wave)
        #pragma unroll
        for (int off = 1; off < 8; off <<= 1) {
            pl += __shfl_xor(pl, off, 64);
            pr += __shfl_xor(pr, off, 64);
        }
        if ((t & 7) == 0) {
            el[(n0 + n) * 4 + hd] = pl;
            er[(n0 + n) * 4 + hd] = pr;
        }
    }
}

// Fused softmax + aggregation + ELU. One 64-lane wave per dst node.
// 256 threads = 4 waves = 4 nodes per block; grid = 12500.
// Softmax computed without max-subtraction (invariant; |e| is O(1) here).
__global__ void gat_aggregate(const int* __restrict__ row_start, const int* __restrict__ csr_src,
                              const float* __restrict__ feat, const float* __restrict__ el,
                              const float* __restrict__ er, float* __restrict__ hout) {
    int lane = threadIdx.x & 63;
    int d = blockIdx.x * 4 + (threadIdx.x >> 6);
    int beg = row_start[d], end = row_start[d + 1];
    int j = lane >> 2;           // edge slot 0..15
    int h = lane & 3;            // head (for ex phase)
    float er_h = er[d * 4 + h];
    int hc = lane >> 4;          // head of this lane's channel pair (c=2*lane,2*lane+1)
    float accx = 0.f, accy = 0.f, dsum = 0.f;
    for (int base = beg; base < end; base += 16) {
        int idx = base + j;
        bool valid = idx < end;
        int s = csr_src[valid ? idx : beg];
        float ev = el[s * 4 + h] + er_h;
        ev = ev > 0.f ? ev : NEG_SLOPE * ev;
        float ex = valid ? __expf(ev) : 0.f;
        dsum += ex;
        int cnt = min(16, end - base);
        for (int jj = 0; jj < cnt; ++jj) {
            int   sj  = __shfl(s,  jj * 4, 64);
            float exj = __shfl(ex, jj * 4 + hc, 64);
            float2 f = ((const float2*)(feat + (size_t)sj * 128))[lane];
            accx += f.x * exj;
            accy += f.y * exj;
        }
    }
    // denom per head: sum over lanes sharing (lane & 3)
    #pragma unroll
    for (int off = 4; off < 64; off <<= 1) dsum += __shfl_xor(dsum, off, 64);
    float dh = __shfl(dsum, hc, 64);     // lane 'hc' holds denom of head hc
    float inv = 1.f / (dh + 1e-10f);
    float ox = accx * inv, oy = accy * inv;
    ox = ox > 0.f ? ox : expm1f(ox);
    oy = oy > 0.f ? oy : expm1f(oy);
    float2 o = {ox, oy};
    ((float2*)(hout + (size_t)d * 128))[lane] = o;
}

// ---------------- pooling / loss ----------------

__global__ void pool_kernel(const int* __restrict__ gid, const float* __restrict__ h,
                            unsigned* __restrict__ pkeys) {
    int i = blockIdx.x * 256 + threadIdx.x;   // N*128
    int n = i >> 7, c = i & 127;
    atomicMax(pkeys + gid[n] * 128 + c, fkey(h[i]));
}

__global__ void logits_kernel(const unsigned* __restrict__ pkeys, const float* __restrict__ w,
                              const float* __restrict__ bptr, float* __restrict__ logits) {
    int g = blockIdx.x, t = threadIdx.x;      // 64 blocks x 64 threads
    float sum = 0.f;
    for (int c = t; c < 128; c += 64) {
        unsigned k = pkeys[g * 128 + c];
        float v = (k == 0u) ? 0.f : kval(k);
        sum += v * w[c];
    }
    #pragma unroll
    for (int off = 32; off; off >>= 1) sum += __shfl_down(sum, off, 64);
    if (t == 0) logits[g] = sum + bptr[0];
}

__global__ void final_kernel(const float* __restrict__ logits, const float* __restrict__ y,
                             float* __restrict__ out) {
    int t = threadIdx.x;  // 64
    float l = logits[t];
    float term = fmaxf(l, 0.f) - l * y[t] + log1pf(expf(-fabsf(l)));
    float s = term;
    #pragma unroll
    for (int off = 32; off; off >>= 1) s += __shfl_down(s, off, 64);
    out[1 + t] = 1.f / (1.f + expf(-l));
    if (t == 0) out[0] = s * (1.f / 64.f);
}

extern "C" void kernel_launch(void* const* d_in, const int* in_sizes, int n_in,
                              void* d_out, int out_size, void* d_ws, size_t ws_size,
                              hipStream_t stream) {
    const int* word_ids  = (const int*)d_in[0];
    const int* esrc      = (const int*)d_in[1];
    const int* edst      = (const int*)d_in[2];
    const int* gid       = (const int*)d_in[3];
    const float* y_data  = (const float*)d_in[4];
    const float* emb     = (const float*)d_in[5];
    const float* W0      = (const float*)d_in[6];
    const float* al0     = (const float*)d_in[7];
    const float* ar0     = (const float*)d_in[8];
    const float* W1      = (const float*)d_in[9];
    const float* al1     = (const float*)d_in[10];
    const float* ar1     = (const float*)d_in[11];
    const float* out_w   = (const float*)d_in[12];
    const float* out_b   = (const float*)d_in[13];
    float* out = (float*)d_out;

    // workspace layout (float offsets); ~57 MB total
    float* ws = (float*)d_ws;
    float*    feat   = ws;                           // 6,400,000
    float*    hbuf   = ws + 6400000;                 // 6,400,000
    float*    el     = ws + 12800000;                // 200,000
    float*    er     = ws + 13000000;                // 200,000
    int*      row_st = (int*)(ws + 13200000);        // 50,001
    int*      deg    = (int*)(ws + 13251000);        // 50,000
    int*      cursor = (int*)(ws + 13301000);        // 50,000
    int*      csrsrc = (int*)(ws + 13351000);        // 800,000
    unsigned* pkeys  = (unsigned*)(ws + 14151000);   // 8,192
    float*    logits = ws + 14159192;                // 64

    // CSR build (shared by both layers)
    hipMemsetAsync(deg, 0, (size_t)N_NODES * 4, stream);
    hist_kernel<<<3125, 256, 0, stream>>>(edst, deg);
    scan_kernel<<<1, 1024, 0, stream>>>(deg, row_st, cursor);
    scatter_kernel<<<3125, 256, 0, stream>>>(esrc, edst, cursor, csrsrc);

    gather_kernel<<<6250, 256, 0, stream>>>(word_ids, (const float4*)emb, (float4*)hbuf);

    auto layer = [&](const float* W, const float* al, const float* ar) {
        feat_kernel<<<3125, 256, 0, stream>>>(hbuf, W, al, ar, feat, el, er);
        gat_aggregate<<<12500, 256, 0, stream>>>(row_st, csrsrc, feat, el, er, hbuf);
    };
    layer(W0, al0, ar0);
    layer(W1, al1, ar1);

    hipMemsetAsync(pkeys, 0, (size_t)N_GRAPHS * 128 * 4, stream);
    pool_kernel<<<25000, 256, 0, stream>>>(gid, hbuf, pkeys);
    logits_kernel<<<N_GRAPHS, 64, 0, stream>>>(pkeys, out_w, out_b, logits);
    final_kernel<<<1, 64, 0, stream>>>(logits, y_data, out);
}

// Round 5
// 568.831 us; speedup vs baseline: 1.2011x; 1.2011x over previous
//
#include <hip/hip_runtime.h>
#include <math.h>

#define N_NODES 50000
#define N_EDGES 800000
#define HEADS 4
#define N_GRAPHS 64
#define NEG_SLOPE 0.2f
#define SCAN_NB 196            // 196*256 = 50176 >= N_NODES

// monotone float<->uint key for atomicMax-based segment max (pooling).
// key==0 is smaller than key(x) for any finite float x.
__device__ __forceinline__ unsigned fkey(float f) {
    unsigned u = __float_as_uint(f);
    return (u & 0x80000000u) ? ~u : (u | 0x80000000u);
}
__device__ __forceinline__ float kval(unsigned k) {
    unsigned u = (k & 0x80000000u) ? (k & 0x7FFFFFFFu) : ~k;
    return __uint_as_float(u);
}

// ---------------- CSR build (counting sort by dst) ----------------

__global__ void hist_kernel(const int* __restrict__ dst, int* __restrict__ deg) {
    int e = blockIdx.x * 256 + threadIdx.x;
    if (e < N_EDGES) atomicAdd(&deg[dst[e]], 1);
}

// pass 1: per-block sums of deg (256 elements/block)
__global__ void partial_kernel(const int* __restrict__ deg, int* __restrict__ partial) {
    int t = threadIdx.x, b = blockIdx.x;
    int i = b * 256 + t;
    int v = (i < N_NODES) ? deg[i] : 0;
    #pragma unroll
    for (int off = 1; off < 64; off <<= 1) v += __shfl_xor(v, off, 64);
    __shared__ int wsum[4];
    if ((t & 63) == 0) wsum[t >> 6] = v;
    __syncthreads();
    if (t == 0) partial[b] = wsum[0] + wsum[1] + wsum[2] + wsum[3];
}

// pass 2: one block scans partial[SCAN_NB] -> exclusive boff
__global__ void boff_kernel(const int* __restrict__ partial, int* __restrict__ boff) {
    __shared__ int wsum[4];
    int t = threadIdx.x;          // 256
    int lane = t & 63, w = t >> 6;
    int v = (t < SCAN_NB) ? partial[t] : 0;
    int incl = v;
    #pragma unroll
    for (int off = 1; off < 64; off <<= 1) {
        int u = __shfl_up(incl, off, 64);
        if (lane >= off) incl += u;
    }
    if (lane == 63) wsum[w] = incl;
    __syncthreads();
    int woff = 0;
    #pragma unroll
    for (int k = 0; k < 4; ++k) if (k < w) woff += wsum[k];
    if (t < SCAN_NB) boff[t] = woff + incl - v;
}

// pass 3: block-level exclusive scan of deg + boff -> row_start, cursor
__global__ void csr_offsets_kernel(const int* __restrict__ deg, const int* __restrict__ boff,
                                   int* __restrict__ row_start, int* __restrict__ cursor) {
    __shared__ int wsum[4];
    int t = threadIdx.x, b = blockIdx.x;
    int lane = t & 63, w = t >> 6;
    int i = b * 256 + t;
    int v = (i < N_NODES) ? deg[i] : 0;
    int incl = v;
    #pragma unroll
    for (int off = 1; off < 64; off <<= 1) {
        int u = __shfl_up(incl, off, 64);
        if (lane >= off) incl += u;
    }
    if (lane == 63) wsum[w] = incl;
    __syncthreads();
    int woff = boff[b];
    #pragma unroll
    for (int k = 0; k < 4; ++k) if (k < w) woff += wsum[k];
    int excl = woff + incl - v;
    if (i < N_NODES) { row_start[i] = excl; cursor[i] = excl; }
    else if (i == N_NODES) row_start[i] = excl;   // == N_EDGES
}

__global__ void scatter_kernel(const int* __restrict__ src, const int* __restrict__ dst,
                               int* __restrict__ cursor, int* __restrict__ csr_src) {
    int e = blockIdx.x * 256 + threadIdx.x;
    if (e < N_EDGES) {
        int p = atomicAdd(&cursor[dst[e]], 1);
        csr_src[p] = src[e];
    }
}

// ---------------- node pipeline ----------------

// h0[n,:] = embeds[word_ids[n],:]  (float4; 32 float4 per row)
__global__ void gather_kernel(const int* __restrict__ wid, const float4* __restrict__ emb4,
                              float4* __restrict__ h4) {
    int i = blockIdx.x * 256 + threadIdx.x;   // N*32 threads exactly
    int n = i >> 5, q = i & 31;
    h4[i] = emb4[wid[n] * 32 + q];
}

// feat = h @ W (128x128) with W staged in LDS; el/er head dots fused.
// 256 threads, 16 nodes per block, grid = 3125.
__global__ void feat_kernel(const float* __restrict__ h, const float* __restrict__ W,
                            const float* __restrict__ al, const float* __restrict__ ar,
                            float* __restrict__ feat, float* __restrict__ el,
                            float* __restrict__ er) {
    __shared__ float Wl[128 * 128];      // 64 KB
    __shared__ float hl[16][128];        // 8 KB
    int t = threadIdx.x;
    {   // stage W: 4096 float4 / 256 threads = 16 each
        const float4* W4 = (const float4*)W;
        float4* Wl4 = (float4*)Wl;
        #pragma unroll
        for (int i = 0; i < 16; ++i) Wl4[t + 256 * i] = W4[t + 256 * i];
    }
    int n0 = blockIdx.x * 16;
    {   // stage h tile: 512 float4 / 256 threads = 2 each
        const float4* h4 = (const float4*)(h + (size_t)n0 * 128);
        float4* hl4 = (float4*)hl;
        hl4[t] = h4[t];
        hl4[t + 256] = h4[t + 256];
    }
    __syncthreads();
    int cg = (t & 31) * 4;       // channel group (4 consecutive channels)
    int nl = t >> 5;             // local node 0..7
    int hd = (t & 31) >> 3;      // head of this channel group
    float al0 = al[cg], al1 = al[cg + 1], al2 = al[cg + 2], al3 = al[cg + 3];
    float ar0 = ar[cg], ar1 = ar[cg + 1], ar2 = ar[cg + 2], ar3 = ar[cg + 3];
    #pragma unroll
    for (int rep = 0; rep < 2; ++rep) {
        int n = nl + 8 * rep;
        float4 acc = {0.f, 0.f, 0.f, 0.f};
        #pragma unroll 16
        for (int k = 0; k < 128; ++k) {
            float hv = hl[n][k];
            float4 w4 = *(const float4*)&Wl[k * 128 + cg];
            acc.x += hv * w4.x; acc.y += hv * w4.y;
            acc.z += hv * w4.z; acc.w += hv * w4.w;
        }
        *(float4*)(feat + (size_t)(n0 + n) * 128 + cg) = acc;
        float pl = acc.x * al0 + acc.y * al1 + acc.z * al2 + acc.w * al3;
        float pr = acc.x * ar0 + acc.y * ar1 + acc.z * ar2 + acc.w * ar3;
        // reduce over the 8 threads covering one head (contiguous lanes, same wave)
        #pragma unroll
        for (int off = 1; off < 8; off <<= 1) {
            pl += __shfl_xor(pl, off, 64);
            pr += __shfl_xor(pr, off, 64);
        }
        if ((t & 7) == 0) {
            el[(n0 + n) * 4 + hd] = pl;
            er[(n0 + n) * 4 + hd] = pr;
        }
    }
}

// Fused softmax + aggregation + ELU. One 64-lane wave per dst node.
// 256 threads = 4 waves = 4 nodes per block; grid = 12500.
// Softmax computed without max-subtraction (invariant; |e| is O(1) here).
__global__ void gat_aggregate(const int* __restrict__ row_start, const int* __restrict__ csr_src,
                              const float* __restrict__ feat, const float* __restrict__ el,
                              const float* __restrict__ er, float* __restrict__ hout) {
    int lane = threadIdx.x & 63;
    int d = blockIdx.x * 4 + (threadIdx.x >> 6);
    int beg = row_start[d], end = row_start[d + 1];
    int j = lane >> 2;           // edge slot 0..15
    int h = lane & 3;            // head (for ex phase)
    float er_h = er[d * 4 + h];
    int hc = lane >> 4;          // head of this lane's channel pair (c=2*lane,2*lane+1)
    float accx = 0.f, accy = 0.f, dsum = 0.f;
    for (int base = beg; base < end; base += 16) {
        int idx = base + j;
        bool valid = idx < end;
        int s = csr_src[valid ? idx : beg];
        float ev = el[s * 4 + h] + er_h;
        ev = ev > 0.f ? ev : NEG_SLOPE * ev;
        float ex = valid ? __expf(ev) : 0.f;
        dsum += ex;
        int cnt = min(16, end - base);
        for (int jj = 0; jj < cnt; ++jj) {
            int   sj  = __shfl(s,  jj * 4, 64);
            float exj = __shfl(ex, jj * 4 + hc, 64);
            float2 f = ((const float2*)(feat + (size_t)sj * 128))[lane];
            accx += f.x * exj;
            accy += f.y * exj;
        }
    }
    // denom per head: sum over lanes sharing (lane & 3)
    #pragma unroll
    for (int off = 4; off < 64; off <<= 1) dsum += __shfl_xor(dsum, off, 64);
    float dh = __shfl(dsum, hc, 64);     // lane 'hc' holds denom of head hc
    float inv = 1.f / (dh + 1e-10f);
    float ox = accx * inv, oy = accy * inv;
    ox = ox > 0.f ? ox : expm1f(ox);
    oy = oy > 0.f ? oy : expm1f(oy);
    float2 o = {ox, oy};
    ((float2*)(hout + (size_t)d * 128))[lane] = o;
}

// ---------------- pooling / loss ----------------

__global__ void pool_kernel(const int* __restrict__ gid, const float* __restrict__ h,
                            unsigned* __restrict__ pkeys) {
    int i = blockIdx.x * 256 + threadIdx.x;   // N*128
    int n = i >> 7, c = i & 127;
    atomicMax(pkeys + gid[n] * 128 + c, fkey(h[i]));
}

__global__ void logits_kernel(const unsigned* __restrict__ pkeys, const float* __restrict__ w,
                              const float* __restrict__ bptr, float* __restrict__ logits) {
    int g = blockIdx.x, t = threadIdx.x;      // 64 blocks x 64 threads
    float sum = 0.f;
    for (int c = t; c < 128; c += 64) {
        unsigned k = pkeys[g * 128 + c];
        float v = (k == 0u) ? 0.f : kval(k);
        sum += v * w[c];
    }
    #pragma unroll
    for (int off = 32; off; off >>= 1) sum += __shfl_down(sum, off, 64);
    if (t == 0) logits[g] = sum + bptr[0];
}

__global__ void final_kernel(const float* __restrict__ logits, const float* __restrict__ y,
                             float* __restrict__ out) {
    int t = threadIdx.x;  // 64
    float l = logits[t];
    float term = fmaxf(l, 0.f) - l * y[t] + log1pf(expf(-fabsf(l)));
    float s = term;
    #pragma unroll
    for (int off = 32; off; off >>= 1) s += __shfl_down(s, off, 64);
    out[1 + t] = 1.f / (1.f + expf(-l));
    if (t == 0) out[0] = s * (1.f / 64.f);
}

extern "C" void kernel_launch(void* const* d_in, const int* in_sizes, int n_in,
                              void* d_out, int out_size, void* d_ws, size_t ws_size,
                              hipStream_t stream) {
    const int* word_ids  = (const int*)d_in[0];
    const int* esrc      = (const int*)d_in[1];
    const int* edst      = (const int*)d_in[2];
    const int* gid       = (const int*)d_in[3];
    const float* y_data  = (const float*)d_in[4];
    const float* emb     = (const float*)d_in[5];
    const float* W0      = (const float*)d_in[6];
    const float* al0     = (const float*)d_in[7];
    const float* ar0     = (const float*)d_in[8];
    const float* W1      = (const float*)d_in[9];
    const float* al1     = (const float*)d_in[10];
    const float* ar1     = (const float*)d_in[11];
    const float* out_w   = (const float*)d_in[12];
    const float* out_b   = (const float*)d_in[13];
    float* out = (float*)d_out;

    // workspace layout (float offsets); ~57 MB total
    float* ws = (float*)d_ws;
    float*    feat   = ws;                           // 6,400,000
    float*    hbuf   = ws + 6400000;                 // 6,400,000
    float*    el     = ws + 12800000;                // 200,000
    float*    er     = ws + 13000000;                // 200,000
    int*      row_st = (int*)(ws + 13200000);        // 50,001
    int*      deg    = (int*)(ws + 13251000);        // 50,000
    int*      cursor = (int*)(ws + 13301000);        // 50,000
    int*      csrsrc = (int*)(ws + 13351000);        // 800,000
    int*      partial= (int*)(ws + 14151000);        // 196
    int*      boff   = (int*)(ws + 14151200);        // 196
    unsigned* pkeys  = (unsigned*)(ws + 14151400);   // 8,192
    float*    logits = ws + 14159592;                // 64

    // CSR build (shared by both layers)
    hipMemsetAsync(deg, 0, (size_t)N_NODES * 4, stream);
    hist_kernel<<<3125, 256, 0, stream>>>(edst, deg);
    partial_kernel<<<SCAN_NB, 256, 0, stream>>>(deg, partial);
    boff_kernel<<<1, 256, 0, stream>>>(partial, boff);
    csr_offsets_kernel<<<SCAN_NB, 256, 0, stream>>>(deg, boff, row_st, cursor);
    scatter_kernel<<<3125, 256, 0, stream>>>(esrc, edst, cursor, csrsrc);

    gather_kernel<<<6250, 256, 0, stream>>>(word_ids, (const float4*)emb, (float4*)hbuf);

    auto layer = [&](const float* W, const float* al, const float* ar) {
        feat_kernel<<<3125, 256, 0, stream>>>(hbuf, W, al, ar, feat, el, er);
        gat_aggregate<<<12500, 256, 0, stream>>>(row_st, csrsrc, feat, el, er, hbuf);
    };
    layer(W0, al0, ar0);
    layer(W1, al1, ar1);

    hipMemsetAsync(pkeys, 0, (size_t)N_GRAPHS * 128 * 4, stream);
    pool_kernel<<<25000, 256, 0, stream>>>(gid, hbuf, pkeys);
    logits_kernel<<<N_GRAPHS, 64, 0, stream>>>(pkeys, out_w, out_b, logits);
    final_kernel<<<1, 64, 0, stream>>>(logits, y_data, out);
}

// Round 6
// 516.317 us; speedup vs baseline: 1.3233x; 1.1017x over previous
//
#include <hip/hip_runtime.h>
#include <math.h>

#define N_NODES 50000
#define N_EDGES 800000
#define HEADS 4
#define N_GRAPHS 64
#define NEG_SLOPE 0.2f
#define SCAN_NB 196            // 196*256 = 50176 >= N_NODES
#define POOL_CHUNK 200
#define POOL_NB 250            // 250*200 = 50000 exactly

// monotone float<->uint key for atomicMax-based segment max (pooling).
// key==0 is smaller than key(x) for any finite float x.
__device__ __forceinline__ unsigned fkey(float f) {
    unsigned u = __float_as_uint(f);
    return (u & 0x80000000u) ? ~u : (u | 0x80000000u);
}
__device__ __forceinline__ float kval(unsigned k) {
    unsigned u = (k & 0x80000000u) ? (k & 0x7FFFFFFFu) : ~k;
    return __uint_as_float(u);
}

// ---------------- CSR build (counting sort by dst) ----------------

__global__ void hist_kernel(const int* __restrict__ dst, int* __restrict__ deg) {
    int e = blockIdx.x * 256 + threadIdx.x;
    if (e < N_EDGES) atomicAdd(&deg[dst[e]], 1);
}

// pass 1: per-block sums of deg (256 elements/block)
__global__ void partial_kernel(const int* __restrict__ deg, int* __restrict__ partial) {
    int t = threadIdx.x, b = blockIdx.x;
    int i = b * 256 + t;
    int v = (i < N_NODES) ? deg[i] : 0;
    #pragma unroll
    for (int off = 1; off < 64; off <<= 1) v += __shfl_xor(v, off, 64);
    __shared__ int wsum[4];
    if ((t & 63) == 0) wsum[t >> 6] = v;
    __syncthreads();
    if (t == 0) partial[b] = wsum[0] + wsum[1] + wsum[2] + wsum[3];
}

// pass 2: one block scans partial[SCAN_NB] -> exclusive boff
__global__ void boff_kernel(const int* __restrict__ partial, int* __restrict__ boff) {
    __shared__ int wsum[4];
    int t = threadIdx.x;          // 256
    int lane = t & 63, w = t >> 6;
    int v = (t < SCAN_NB) ? partial[t] : 0;
    int incl = v;
    #pragma unroll
    for (int off = 1; off < 64; off <<= 1) {
        int u = __shfl_up(incl, off, 64);
        if (lane >= off) incl += u;
    }
    if (lane == 63) wsum[w] = incl;
    __syncthreads();
    int woff = 0;
    #pragma unroll
    for (int k = 0; k < 4; ++k) if (k < w) woff += wsum[k];
    if (t < SCAN_NB) boff[t] = woff + incl - v;
}

// pass 3: block-level exclusive scan of deg + boff -> row_start, cursor
__global__ void csr_offsets_kernel(const int* __restrict__ deg, const int* __restrict__ boff,
                                   int* __restrict__ row_start, int* __restrict__ cursor) {
    __shared__ int wsum[4];
    int t = threadIdx.x, b = blockIdx.x;
    int lane = t & 63, w = t >> 6;
    int i = b * 256 + t;
    int v = (i < N_NODES) ? deg[i] : 0;
    int incl = v;
    #pragma unroll
    for (int off = 1; off < 64; off <<= 1) {
        int u = __shfl_up(incl, off, 64);
        if (lane >= off) incl += u;
    }
    if (lane == 63) wsum[w] = incl;
    __syncthreads();
    int woff = boff[b];
    #pragma unroll
    for (int k = 0; k < 4; ++k) if (k < w) woff += wsum[k];
    int excl = woff + incl - v;
    if (i < N_NODES) { row_start[i] = excl; cursor[i] = excl; }
    else if (i == N_NODES) row_start[i] = excl;   // == N_EDGES
}

__global__ void scatter_kernel(const int* __restrict__ src, const int* __restrict__ dst,
                               int* __restrict__ cursor, int* __restrict__ csr_src) {
    int e = blockIdx.x * 256 + threadIdx.x;
    if (e < N_EDGES) {
        int p = atomicAdd(&cursor[dst[e]], 1);
        csr_src[p] = src[e];
    }
}

// ---------------- node pipeline ----------------

// h0[n,:] = embeds[word_ids[n],:]  (float4; 32 float4 per row)
__global__ void gather_kernel(const int* __restrict__ wid, const float4* __restrict__ emb4,
                              float4* __restrict__ h4) {
    int i = blockIdx.x * 256 + threadIdx.x;   // N*32 threads exactly
    int n = i >> 5, q = i & 31;
    h4[i] = emb4[wid[n] * 32 + q];
}

// feat = h @ W (128x128) with W staged in LDS; el/er head dots fused.
// 256 threads, 16 nodes per block, grid = 3125.
__global__ void feat_kernel(const float* __restrict__ h, const float* __restrict__ W,
                            const float* __restrict__ al, const float* __restrict__ ar,
                            float* __restrict__ feat, float* __restrict__ el,
                            float* __restrict__ er) {
    __shared__ float Wl[128 * 128];      // 64 KB
    __shared__ float hl[16][128];        // 8 KB
    int t = threadIdx.x;
    {   // stage W: 4096 float4 / 256 threads = 16 each
        const float4* W4 = (const float4*)W;
        float4* Wl4 = (float4*)Wl;
        #pragma unroll
        for (int i = 0; i < 16; ++i) Wl4[t + 256 * i] = W4[t + 256 * i];
    }
    int n0 = blockIdx.x * 16;
    {   // stage h tile: 512 float4 / 256 threads = 2 each
        const float4* h4 = (const float4*)(h + (size_t)n0 * 128);
        float4* hl4 = (float4*)hl;
        hl4[t] = h4[t];
        hl4[t + 256] = h4[t + 256];
    }
    __syncthreads();
    int cg = (t & 31) * 4;       // channel group (4 consecutive channels)
    int nl = t >> 5;             // local node 0..7
    int hd = (t & 31) >> 3;      // head of this channel group
    float al0 = al[cg], al1 = al[cg + 1], al2 = al[cg + 2], al3 = al[cg + 3];
    float ar0 = ar[cg], ar1 = ar[cg + 1], ar2 = ar[cg + 2], ar3 = ar[cg + 3];
    #pragma unroll
    for (int rep = 0; rep < 2; ++rep) {
        int n = nl + 8 * rep;
        float4 acc = {0.f, 0.f, 0.f, 0.f};
        #pragma unroll 16
        for (int k = 0; k < 128; ++k) {
            float hv = hl[n][k];
            float4 w4 = *(const float4*)&Wl[k * 128 + cg];
            acc.x += hv * w4.x; acc.y += hv * w4.y;
            acc.z += hv * w4.z; acc.w += hv * w4.w;
        }
        *(float4*)(feat + (size_t)(n0 + n) * 128 + cg) = acc;
        float pl = acc.x * al0 + acc.y * al1 + acc.z * al2 + acc.w * al3;
        float pr = acc.x * ar0 + acc.y * ar1 + acc.z * ar2 + acc.w * ar3;
        // reduce over the 8 threads covering one head (contiguous lanes, same wave)
        #pragma unroll
        for (int off = 1; off < 8; off <<= 1) {
            pl += __shfl_xor(pl, off, 64);
            pr += __shfl_xor(pr, off, 64);
        }
        if ((t & 7) == 0) {
            el[(n0 + n) * 4 + hd] = pl;
            er[(n0 + n) * 4 + hd] = pr;
        }
    }
}

// Fused softmax + aggregation + ELU. One 64-lane wave per dst node.
// 256 threads = 4 waves = 4 nodes per block; grid = 12500.
// Softmax computed without max-subtraction (invariant; |e| is O(1) here).
__global__ void gat_aggregate(const int* __restrict__ row_start, const int* __restrict__ csr_src,
                              const float* __restrict__ feat, const float* __restrict__ el,
                              const float* __restrict__ er, float* __restrict__ hout) {
    int lane = threadIdx.x & 63;
    int d = blockIdx.x * 4 + (threadIdx.x >> 6);
    int beg = row_start[d], end = row_start[d + 1];
    int j = lane >> 2;           // edge slot 0..15
    int h = lane & 3;            // head (for ex phase)
    float er_h = er[d * 4 + h];
    int hc = lane >> 4;          // head of this lane's channel pair (c=2*lane,2*lane+1)
    float accx = 0.f, accy = 0.f, dsum = 0.f;
    for (int base = beg; base < end; base += 16) {
        int idx = base + j;
        bool valid = idx < end;
        int s = csr_src[valid ? idx : beg];
        float ev = el[s * 4 + h] + er_h;
        ev = ev > 0.f ? ev : NEG_SLOPE * ev;
        float ex = valid ? __expf(ev) : 0.f;
        dsum += ex;
        int cnt = min(16, end - base);
        for (int jj = 0; jj < cnt; ++jj) {
            int   sj  = __shfl(s,  jj * 4, 64);
            float exj = __shfl(ex, jj * 4 + hc, 64);
            float2 f = ((const float2*)(feat + (size_t)sj * 128))[lane];
            accx += f.x * exj;
            accy += f.y * exj;
        }
    }
    // denom per head: sum over lanes sharing (lane & 3)
    #pragma unroll
    for (int off = 4; off < 64; off <<= 1) dsum += __shfl_xor(dsum, off, 64);
    float dh = __shfl(dsum, hc, 64);     // lane 'hc' holds denom of head hc
    float inv = 1.f / (dh + 1e-10f);
    float ox = accx * inv, oy = accy * inv;
    ox = ox > 0.f ? ox : expm1f(ox);
    oy = oy > 0.f ? oy : expm1f(oy);
    float2 o = {ox, oy};
    ((float2*)(hout + (size_t)d * 128))[lane] = o;
}

// ---------------- pooling / loss ----------------

// node_graph_id is SORTED -> each block scans 200 contiguous nodes keeping a
// register max per channel, flushing one atomicMax per gid transition.
// thread = (parity, channel): c = t&127, parity = t>>7.
__global__ void pool_kernel(const int* __restrict__ gid, const float* __restrict__ h,
                            unsigned* __restrict__ pkeys) {
    int t = threadIdx.x;
    int c = t & 127;
    int par = t >> 7;              // 0/1
    int n0 = blockIdx.x * POOL_CHUNK;
    float m = 0.f;
    int cur_g = -1;
    for (int n = n0 + par; n < n0 + POOL_CHUNK; n += 2) {
        int g = gid[n];
        if (g != cur_g) {
            if (cur_g >= 0) atomicMax(&pkeys[cur_g * 128 + c], fkey(m));
            cur_g = g;
            m = -3.0e38f;
        }
        m = fmaxf(m, h[(size_t)n * 128 + c]);
    }
    if (cur_g >= 0) atomicMax(&pkeys[cur_g * 128 + c], fkey(m));
}

__global__ void logits_kernel(const unsigned* __restrict__ pkeys, const float* __restrict__ w,
                              const float* __restrict__ bptr, float* __restrict__ logits) {
    int g = blockIdx.x, t = threadIdx.x;      // 64 blocks x 64 threads
    float sum = 0.f;
    for (int c = t; c < 128; c += 64) {
        unsigned k = pkeys[g * 128 + c];
        float v = (k == 0u) ? 0.f : kval(k);
        sum += v * w[c];
    }
    #pragma unroll
    for (int off = 32; off; off >>= 1) sum += __shfl_down(sum, off, 64);
    if (t == 0) logits[g] = sum + bptr[0];
}

__global__ void final_kernel(const float* __restrict__ logits, const float* __restrict__ y,
                             float* __restrict__ out) {
    int t = threadIdx.x;  // 64
    float l = logits[t];
    float term = fmaxf(l, 0.f) - l * y[t] + log1pf(expf(-fabsf(l)));
    float s = term;
    #pragma unroll
    for (int off = 32; off; off >>= 1) s += __shfl_down(s, off, 64);
    out[1 + t] = 1.f / (1.f + expf(-l));
    if (t == 0) out[0] = s * (1.f / 64.f);
}

extern "C" void kernel_launch(void* const* d_in, const int* in_sizes, int n_in,
                              void* d_out, int out_size, void* d_ws, size_t ws_size,
                              hipStream_t stream) {
    const int* word_ids  = (const int*)d_in[0];
    const int* esrc      = (const int*)d_in[1];
    const int* edst      = (const int*)d_in[2];
    const int* gid       = (const int*)d_in[3];
    const float* y_data  = (const float*)d_in[4];
    const float* emb     = (const float*)d_in[5];
    const float* W0      = (const float*)d_in[6];
    const float* al0     = (const float*)d_in[7];
    const float* ar0     = (const float*)d_in[8];
    const float* W1      = (const float*)d_in[9];
    const float* al1     = (const float*)d_in[10];
    const float* ar1     = (const float*)d_in[11];
    const float* out_w   = (const float*)d_in[12];
    const float* out_b   = (const float*)d_in[13];
    float* out = (float*)d_out;

    // workspace layout (float offsets); ~57 MB total
    float* ws = (float*)d_ws;
    float*    feat   = ws;                           // 6,400,000
    float*    hbuf   = ws + 6400000;                 // 6,400,000
    float*    el     = ws + 12800000;                // 200,000
    float*    er     = ws + 13000000;                // 200,000
    int*      row_st = (int*)(ws + 13200000);        // 50,001
    int*      deg    = (int*)(ws + 13251000);        // 50,000
    int*      cursor = (int*)(ws + 13301000);        // 50,000
    int*      csrsrc = (int*)(ws + 13351000);        // 800,000
    int*      partial= (int*)(ws + 14151000);        // 196
    int*      boff   = (int*)(ws + 14151200);        // 196
    unsigned* pkeys  = (unsigned*)(ws + 14151400);   // 8,192
    float*    logits = ws + 14159592;                // 64

    // CSR build (shared by both layers)
    hipMemsetAsync(deg, 0, (size_t)N_NODES * 4, stream);
    hist_kernel<<<3125, 256, 0, stream>>>(edst, deg);
    partial_kernel<<<SCAN_NB, 256, 0, stream>>>(deg, partial);
    boff_kernel<<<1, 256, 0, stream>>>(partial, boff);
    csr_offsets_kernel<<<SCAN_NB, 256, 0, stream>>>(deg, boff, row_st, cursor);
    scatter_kernel<<<3125, 256, 0, stream>>>(esrc, edst, cursor, csrsrc);

    gather_kernel<<<6250, 256, 0, stream>>>(word_ids, (const float4*)emb, (float4*)hbuf);

    auto layer = [&](const float* W, const float* al, const float* ar) {
        feat_kernel<<<3125, 256, 0, stream>>>(hbuf, W, al, ar, feat, el, er);
        gat_aggregate<<<12500, 256, 0, stream>>>(row_st, csrsrc, feat, el, er, hbuf);
    };
    layer(W0, al0, ar0);
    layer(W1, al1, ar1);

    hipMemsetAsync(pkeys, 0, (size_t)N_GRAPHS * 128 * 4, stream);
    pool_kernel<<<POOL_NB, 256, 0, stream>>>(gid, hbuf, pkeys);
    logits_kernel<<<N_GRAPHS, 64, 0, stream>>>(pkeys, out_w, out_b, logits);
    final_kernel<<<1, 64, 0, stream>>>(logits, y_data, out);
}

// Round 7
// 432.653 us; speedup vs baseline: 1.5791x; 1.1934x over previous
//
#include <hip/hip_runtime.h>
#include <math.h>

#define N_NODES 50000
#define N_EDGES 800000
#define HEADS 4
#define N_GRAPHS 64
#define NEG_SLOPE 0.2f
#define SCAN_NB 196            // 196*256 = 50176 >= N_NODES
#define POOL_CHUNK 200
#define POOL_NB 250            // 250*200 = 50000 exactly
#define FEAT_NB 1563           // ceil(50000/32)

// monotone float<->uint key for atomicMax-based segment max (pooling).
// key==0 is smaller than key(x) for any finite float x.
__device__ __forceinline__ unsigned fkey(float f) {
    unsigned u = __float_as_uint(f);
    return (u & 0x80000000u) ? ~u : (u | 0x80000000u);
}
__device__ __forceinline__ float kval(unsigned k) {
    unsigned u = (k & 0x80000000u) ? (k & 0x7FFFFFFFu) : ~k;
    return __uint_as_float(u);
}

// ---------------- CSR build (counting sort by dst) ----------------

__global__ void hist_kernel(const int* __restrict__ dst, int* __restrict__ deg) {
    int e = blockIdx.x * 256 + threadIdx.x;
    if (e < N_EDGES) atomicAdd(&deg[dst[e]], 1);
}

// pass 1: per-block sums of deg (256 elements/block)
__global__ void partial_kernel(const int* __restrict__ deg, int* __restrict__ partial) {
    int t = threadIdx.x, b = blockIdx.x;
    int i = b * 256 + t;
    int v = (i < N_NODES) ? deg[i] : 0;
    #pragma unroll
    for (int off = 1; off < 64; off <<= 1) v += __shfl_xor(v, off, 64);
    __shared__ int wsum[4];
    if ((t & 63) == 0) wsum[t >> 6] = v;
    __syncthreads();
    if (t == 0) partial[b] = wsum[0] + wsum[1] + wsum[2] + wsum[3];
}

// pass 2: one block scans partial[SCAN_NB] -> exclusive boff
__global__ void boff_kernel(const int* __restrict__ partial, int* __restrict__ boff) {
    __shared__ int wsum[4];
    int t = threadIdx.x;          // 256
    int lane = t & 63, w = t >> 6;
    int v = (t < SCAN_NB) ? partial[t] : 0;
    int incl = v;
    #pragma unroll
    for (int off = 1; off < 64; off <<= 1) {
        int u = __shfl_up(incl, off, 64);
        if (lane >= off) incl += u;
    }
    if (lane == 63) wsum[w] = incl;
    __syncthreads();
    int woff = 0;
    #pragma unroll
    for (int k = 0; k < 4; ++k) if (k < w) woff += wsum[k];
    if (t < SCAN_NB) boff[t] = woff + incl - v;
}

// pass 3: block-level exclusive scan of deg + boff -> row_start, cursor
__global__ void csr_offsets_kernel(const int* __restrict__ deg, const int* __restrict__ boff,
                                   int* __restrict__ row_start, int* __restrict__ cursor) {
    __shared__ int wsum[4];
    int t = threadIdx.x, b = blockIdx.x;
    int lane = t & 63, w = t >> 6;
    int i = b * 256 + t;
    int v = (i < N_NODES) ? deg[i] : 0;
    int incl = v;
    #pragma unroll
    for (int off = 1; off < 64; off <<= 1) {
        int u = __shfl_up(incl, off, 64);
        if (lane >= off) incl += u;
    }
    if (lane == 63) wsum[w] = incl;
    __syncthreads();
    int woff = boff[b];
    #pragma unroll
    for (int k = 0; k < 4; ++k) if (k < w) woff += wsum[k];
    int excl = woff + incl - v;
    if (i < N_NODES) { row_start[i] = excl; cursor[i] = excl; }
    else if (i == N_NODES) row_start[i] = excl;   // == N_EDGES
}

__global__ void scatter_kernel(const int* __restrict__ src, const int* __restrict__ dst,
                               int* __restrict__ cursor, int* __restrict__ csr_src) {
    int e = blockIdx.x * 256 + threadIdx.x;
    if (e < N_EDGES) {
        int p = atomicAdd(&cursor[dst[e]], 1);
        csr_src[p] = src[e];
    }
}

// ---------------- node pipeline ----------------

// h0[n,:] = embeds[word_ids[n],:]  (float4; 32 float4 per row)
__global__ void gather_kernel(const int* __restrict__ wid, const float4* __restrict__ emb4,
                              float4* __restrict__ h4) {
    int i = blockIdx.x * 256 + threadIdx.x;   // N*32 threads exactly
    int n = i >> 5, q = i & 31;
    h4[i] = emb4[wid[n] * 32 + q];
}

// feat = h @ W (128x128). Register-tiled: 32 nodes/block, 256 threads,
// thread = (ng 0..7, cg 0..31) computes 4 nodes x 4 channels.
// LDS exactly 80 KB (W 64K + h 16K) -> 2 blocks/CU. Per k4-step:
// 4 broadcast b128 A-reads (2 addrs/wave, 2-way = free) + 4 spread b128
// W-reads for 64 FMAs => 2 B/FMA LDS traffic (was 5).
__global__ __launch_bounds__(256, 2)
void feat_kernel(const float* __restrict__ h, const float* __restrict__ W,
                 const float* __restrict__ al, const float* __restrict__ ar,
                 float* __restrict__ feat, float* __restrict__ el,
                 float* __restrict__ er) {
    __shared__ float Wl[128 * 128];      // 64 KB
    __shared__ float hl[32 * 128];       // 16 KB
    int t = threadIdx.x;
    {   // stage W: 4096 float4 / 256 threads = 16 each
        const float4* W4 = (const float4*)W;
        float4* Wl4 = (float4*)Wl;
        #pragma unroll
        for (int i = 0; i < 16; ++i) Wl4[t + 256 * i] = W4[t + 256 * i];
    }
    int n0 = blockIdx.x * 32;
    {   // stage h tile: 1024 float4 / 256 threads = 4 each (zero-fill tail)
        const float4* h4 = (const float4*)h;
        float4* hl4 = (float4*)hl;
        #pragma unroll
        for (int r = 0; r < 4; ++r) {
            int i = t + 256 * r;
            int n = i >> 5, q = i & 31;
            float4 v = {0.f, 0.f, 0.f, 0.f};
            if (n0 + n < N_NODES) v = h4[(size_t)(n0 + n) * 32 + q];
            hl4[n * 32 + q] = v;
        }
    }
    __syncthreads();
    int ng = t >> 5, cg = t & 31;
    const float4* hl4 = (const float4*)hl;
    const float4* Wl4 = (const float4*)Wl;
    float4 acc[4];
    #pragma unroll
    for (int i = 0; i < 4; ++i) acc[i] = {0.f, 0.f, 0.f, 0.f};
    for (int k4 = 0; k4 < 32; ++k4) {
        float4 a0 = hl4[(ng * 4 + 0) * 32 + k4];
        float4 a1 = hl4[(ng * 4 + 1) * 32 + k4];
        float4 a2 = hl4[(ng * 4 + 2) * 32 + k4];
        float4 a3 = hl4[(ng * 4 + 3) * 32 + k4];
        #pragma unroll
        for (int kk = 0; kk < 4; ++kk) {
            float4 w = Wl4[(k4 * 4 + kk) * 32 + cg];
            float c0 = ((const float*)&a0)[kk];
            float c1 = ((const float*)&a1)[kk];
            float c2 = ((const float*)&a2)[kk];
            float c3 = ((const float*)&a3)[kk];
            acc[0].x += c0 * w.x; acc[0].y += c0 * w.y; acc[0].z += c0 * w.z; acc[0].w += c0 * w.w;
            acc[1].x += c1 * w.x; acc[1].y += c1 * w.y; acc[1].z += c1 * w.z; acc[1].w += c1 * w.w;
            acc[2].x += c2 * w.x; acc[2].y += c2 * w.y; acc[2].z += c2 * w.z; acc[2].w += c2 * w.w;
            acc[3].x += c3 * w.x; acc[3].y += c3 * w.y; acc[3].z += c3 * w.z; acc[3].w += c3 * w.w;
        }
    }
    int hd = cg >> 3;            // head of this 4-channel group
    float a0v = al[cg * 4], a1v = al[cg * 4 + 1], a2v = al[cg * 4 + 2], a3v = al[cg * 4 + 3];
    float r0v = ar[cg * 4], r1v = ar[cg * 4 + 1], r2v = ar[cg * 4 + 2], r3v = ar[cg * 4 + 3];
    #pragma unroll
    for (int i = 0; i < 4; ++i) {
        int n = n0 + ng * 4 + i;
        if (n >= N_NODES) break;             // uniform across the 8-lane head group
        *(float4*)(feat + (size_t)n * 128 + cg * 4) = acc[i];
        float pl = acc[i].x * a0v + acc[i].y * a1v + acc[i].z * a2v + acc[i].w * a3v;
        float pr = acc[i].x * r0v + acc[i].y * r1v + acc[i].z * r2v + acc[i].w * r3v;
        #pragma unroll
        for (int off = 1; off < 8; off <<= 1) {
            pl += __shfl_xor(pl, off, 64);
            pr += __shfl_xor(pr, off, 64);
        }
        if ((t & 7) == 0) {
            el[n * 4 + hd] = pl;
            er[n * 4 + hd] = pr;
        }
    }
}

// Fused softmax + aggregation + ELU. One 64-lane wave per dst node.
// 256 threads = 4 waves = 4 nodes per block; grid = 12500.
// Softmax computed without max-subtraction (invariant; |e| is O(1) here).
__global__ void gat_aggregate(const int* __restrict__ row_start, const int* __restrict__ csr_src,
                              const float* __restrict__ feat, const float* __restrict__ el,
                              const float* __restrict__ er, float* __restrict__ hout) {
    int lane = threadIdx.x & 63;
    int d = blockIdx.x * 4 + (threadIdx.x >> 6);
    int beg = row_start[d], end = row_start[d + 1];
    int j = lane >> 2;           // edge slot 0..15
    int h = lane & 3;            // head (for ex phase)
    float er_h = er[d * 4 + h];
    int hc = lane >> 4;          // head of this lane's channel pair (c=2*lane,2*lane+1)
    float accx = 0.f, accy = 0.f, dsum = 0.f;
    for (int base = beg; base < end; base += 16) {
        int idx = base + j;
        bool valid = idx < end;
        int s = csr_src[valid ? idx : beg];
        float ev = el[s * 4 + h] + er_h;
        ev = ev > 0.f ? ev : NEG_SLOPE * ev;
        float ex = valid ? __expf(ev) : 0.f;
        dsum += ex;
        int cnt = min(16, end - base);
        for (int jj = 0; jj < cnt; ++jj) {
            int   sj  = __shfl(s,  jj * 4, 64);
            float exj = __shfl(ex, jj * 4 + hc, 64);
            float2 f = ((const float2*)(feat + (size_t)sj * 128))[lane];
            accx += f.x * exj;
            accy += f.y * exj;
        }
    }
    // denom per head: sum over lanes sharing (lane & 3)
    #pragma unroll
    for (int off = 4; off < 64; off <<= 1) dsum += __shfl_xor(dsum, off, 64);
    float dh = __shfl(dsum, hc, 64);     // lane 'hc' holds denom of head hc
    float inv = 1.f / (dh + 1e-10f);
    float ox = accx * inv, oy = accy * inv;
    ox = ox > 0.f ? ox : expm1f(ox);
    oy = oy > 0.f ? oy : expm1f(oy);
    float2 o = {ox, oy};
    ((float2*)(hout + (size_t)d * 128))[lane] = o;
}

// ---------------- pooling / loss ----------------

// node_graph_id is SORTED -> each block scans 200 contiguous nodes keeping a
// register max per channel, flushing one atomicMax per gid transition.
__global__ void pool_kernel(const int* __restrict__ gid, const float* __restrict__ h,
                            unsigned* __restrict__ pkeys) {
    int t = threadIdx.x;
    int c = t & 127;
    int par = t >> 7;              // 0/1
    int n0 = blockIdx.x * POOL_CHUNK;
    float m = 0.f;
    int cur_g = -1;
    for (int n = n0 + par; n < n0 + POOL_CHUNK; n += 2) {
        int g = gid[n];
        if (g != cur_g) {
            if (cur_g >= 0) atomicMax(&pkeys[cur_g * 128 + c], fkey(m));
            cur_g = g;
            m = -3.0e38f;
        }
        m = fmaxf(m, h[(size_t)n * 128 + c]);
    }
    if (cur_g >= 0) atomicMax(&pkeys[cur_g * 128 + c], fkey(m));
}

__global__ void logits_kernel(const unsigned* __restrict__ pkeys, const float* __restrict__ w,
                              const float* __restrict__ bptr, float* __restrict__ logits) {
    int g = blockIdx.x, t = threadIdx.x;      // 64 blocks x 64 threads
    float sum = 0.f;
    for (int c = t; c < 128; c += 64) {
        unsigned k = pkeys[g * 128 + c];
        float v = (k == 0u) ? 0.f : kval(k);
        sum += v * w[c];
    }
    #pragma unroll
    for (int off = 32; off; off >>= 1) sum += __shfl_down(sum, off, 64);
    if (t == 0) logits[g] = sum + bptr[0];
}

__global__ void final_kernel(const float* __restrict__ logits, const float* __restrict__ y,
                             float* __restrict__ out) {
    int t = threadIdx.x;  // 64
    float l = logits[t];
    float term = fmaxf(l, 0.f) - l * y[t] + log1pf(expf(-fabsf(l)));
    float s = term;
    #pragma unroll
    for (int off = 32; off; off >>= 1) s += __shfl_down(s, off, 64);
    out[1 + t] = 1.f / (1.f + expf(-l));
    if (t == 0) out[0] = s * (1.f / 64.f);
}

extern "C" void kernel_launch(void* const* d_in, const int* in_sizes, int n_in,
                              void* d_out, int out_size, void* d_ws, size_t ws_size,
                              hipStream_t stream) {
    const int* word_ids  = (const int*)d_in[0];
    const int* esrc      = (const int*)d_in[1];
    const int* edst      = (const int*)d_in[2];
    const int* gid       = (const int*)d_in[3];
    const float* y_data  = (const float*)d_in[4];
    const float* emb     = (const float*)d_in[5];
    const float* W0      = (const float*)d_in[6];
    const float* al0     = (const float*)d_in[7];
    const float* ar0     = (const float*)d_in[8];
    const float* W1      = (const float*)d_in[9];
    const float* al1     = (const float*)d_in[10];
    const float* ar1     = (const float*)d_in[11];
    const float* out_w   = (const float*)d_in[12];
    const float* out_b   = (const float*)d_in[13];
    float* out = (float*)d_out;

    // workspace layout (float offsets); ~57 MB total
    float* ws = (float*)d_ws;
    float*    feat   = ws;                           // 6,400,000
    float*    hbuf   = ws + 6400000;                 // 6,400,000
    float*    el     = ws + 12800000;                // 200,000
    float*    er     = ws + 13000000;                // 200,000
    int*      row_st = (int*)(ws + 13200000);        // 50,001
    int*      deg    = (int*)(ws + 13251000);        // 50,000
    int*      cursor = (int*)(ws + 13301000);        // 50,000
    int*      csrsrc = (int*)(ws + 13351000);        // 800,000
    int*      partial= (int*)(ws + 14151000);        // 196
    int*      boff   = (int*)(ws + 14151200);        // 196
    unsigned* pkeys  = (unsigned*)(ws + 14151400);   // 8,192
    float*    logits = ws + 14159592;                // 64

    // CSR build (shared by both layers)
    hipMemsetAsync(deg, 0, (size_t)N_NODES * 4, stream);
    hist_kernel<<<3125, 256, 0, stream>>>(edst, deg);
    partial_kernel<<<SCAN_NB, 256, 0, stream>>>(deg, partial);
    boff_kernel<<<1, 256, 0, stream>>>(partial, boff);
    csr_offsets_kernel<<<SCAN_NB, 256, 0, stream>>>(deg, boff, row_st, cursor);
    scatter_kernel<<<3125, 256, 0, stream>>>(esrc, edst, cursor, csrsrc);

    gather_kernel<<<6250, 256, 0, stream>>>(word_ids, (const float4*)emb, (float4*)hbuf);

    auto layer = [&](const float* W, const float* al, const float* ar) {
        feat_kernel<<<FEAT_NB, 256, 0, stream>>>(hbuf, W, al, ar, feat, el, er);
        gat_aggregate<<<12500, 256, 0, stream>>>(row_st, csrsrc, feat, el, er, hbuf);
    };
    layer(W0, al0, ar0);
    layer(W1, al1, ar1);

    hipMemsetAsync(pkeys, 0, (size_t)N_GRAPHS * 128 * 4, stream);
    pool_kernel<<<POOL_NB, 256, 0, stream>>>(gid, hbuf, pkeys);
    logits_kernel<<<N_GRAPHS, 64, 0, stream>>>(pkeys, out_w, out_b, logits);
    final_kernel<<<1, 64, 0, stream>>>(logits, y_data, out);
}

// Round 8
// 424.224 us; speedup vs baseline: 1.6105x; 1.0199x over previous
//
#include <hip/hip_runtime.h>
#include <math.h>

#define N_NODES 50000
#define N_EDGES 800000
#define HEADS 4
#define N_GRAPHS 64
#define NEG_SLOPE 0.2f
#define SCAN_NB 196            // 196*256 = 50176 >= N_NODES
#define POOL_CHUNK 200
#define POOL_NB 250            // 250*200 = 50000 exactly
#define FEAT_NB 1563           // ceil(50000/32)

// monotone float<->uint key for atomicMax-based segment max (pooling).
__device__ __forceinline__ unsigned fkey(float f) {
    unsigned u = __float_as_uint(f);
    return (u & 0x80000000u) ? ~u : (u | 0x80000000u);
}
__device__ __forceinline__ float kval(unsigned k) {
    unsigned u = (k & 0x80000000u) ? (k & 0x7FFFFFFFu) : ~k;
    return __uint_as_float(u);
}

// f32 -> bf16 (RNE), two packed into one uint (lo = first channel)
__device__ __forceinline__ unsigned short f2bf(float f) {
    unsigned u = __float_as_uint(f);
    u += 0x7FFFu + ((u >> 16) & 1u);
    return (unsigned short)(u >> 16);
}
__device__ __forceinline__ unsigned pack_bf2(float a, float b) {
    return (unsigned)f2bf(a) | ((unsigned)f2bf(b) << 16);
}

// ---------------- CSR build (counting sort by dst) ----------------

__global__ void hist_kernel(const int* __restrict__ dst, int* __restrict__ deg) {
    int e = blockIdx.x * 256 + threadIdx.x;
    if (e < N_EDGES) atomicAdd(&deg[dst[e]], 1);
}

__global__ void partial_kernel(const int* __restrict__ deg, int* __restrict__ partial) {
    int t = threadIdx.x, b = blockIdx.x;
    int i = b * 256 + t;
    int v = (i < N_NODES) ? deg[i] : 0;
    #pragma unroll
    for (int off = 1; off < 64; off <<= 1) v += __shfl_xor(v, off, 64);
    __shared__ int wsum[4];
    if ((t & 63) == 0) wsum[t >> 6] = v;
    __syncthreads();
    if (t == 0) partial[b] = wsum[0] + wsum[1] + wsum[2] + wsum[3];
}

__global__ void boff_kernel(const int* __restrict__ partial, int* __restrict__ boff) {
    __shared__ int wsum[4];
    int t = threadIdx.x;          // 256
    int lane = t & 63, w = t >> 6;
    int v = (t < SCAN_NB) ? partial[t] : 0;
    int incl = v;
    #pragma unroll
    for (int off = 1; off < 64; off <<= 1) {
        int u = __shfl_up(incl, off, 64);
        if (lane >= off) incl += u;
    }
    if (lane == 63) wsum[w] = incl;
    __syncthreads();
    int woff = 0;
    #pragma unroll
    for (int k = 0; k < 4; ++k) if (k < w) woff += wsum[k];
    if (t < SCAN_NB) boff[t] = woff + incl - v;
}

__global__ void csr_offsets_kernel(const int* __restrict__ deg, const int* __restrict__ boff,
                                   int* __restrict__ row_start, int* __restrict__ cursor) {
    __shared__ int wsum[4];
    int t = threadIdx.x, b = blockIdx.x;
    int lane = t & 63, w = t >> 6;
    int i = b * 256 + t;
    int v = (i < N_NODES) ? deg[i] : 0;
    int incl = v;
    #pragma unroll
    for (int off = 1; off < 64; off <<= 1) {
        int u = __shfl_up(incl, off, 64);
        if (lane >= off) incl += u;
    }
    if (lane == 63) wsum[w] = incl;
    __syncthreads();
    int woff = boff[b];
    #pragma unroll
    for (int k = 0; k < 4; ++k) if (k < w) woff += wsum[k];
    int excl = woff + incl - v;
    if (i < N_NODES) { row_start[i] = excl; cursor[i] = excl; }
    else if (i == N_NODES) row_start[i] = excl;   // == N_EDGES
}

__global__ void scatter_kernel(const int* __restrict__ src, const int* __restrict__ dst,
                               int* __restrict__ cursor, int* __restrict__ csr_src) {
    int e = blockIdx.x * 256 + threadIdx.x;
    if (e < N_EDGES) {
        int p = atomicAdd(&cursor[dst[e]], 1);
        csr_src[p] = src[e];
    }
}

// ---------------- node pipeline ----------------

__global__ void gather_kernel(const int* __restrict__ wid, const float4* __restrict__ emb4,
                              float4* __restrict__ h4) {
    int i = blockIdx.x * 256 + threadIdx.x;   // N*32 threads exactly
    int n = i >> 5, q = i & 31;
    h4[i] = emb4[wid[n] * 32 + q];
}

// feat = h @ W (128x128). Register-tiled: 32 nodes/block, 256 threads,
// thread = (ng 0..7, cg 0..31) computes 4 nodes x 4 channels.
// el/er computed from f32 acc; feat stored as packed bf16 (2 ch / uint)
// to halve the gat_aggregate gather traffic.
__global__ __launch_bounds__(256, 2)
void feat_kernel(const float* __restrict__ h, const float* __restrict__ W,
                 const float* __restrict__ al, const float* __restrict__ ar,
                 unsigned* __restrict__ featb, float* __restrict__ el,
                 float* __restrict__ er) {
    __shared__ float Wl[128 * 128];      // 64 KB
    __shared__ float hl[32 * 128];       // 16 KB
    int t = threadIdx.x;
    {   // stage W: 4096 float4 / 256 threads = 16 each
        const float4* W4 = (const float4*)W;
        float4* Wl4 = (float4*)Wl;
        #pragma unroll
        for (int i = 0; i < 16; ++i) Wl4[t + 256 * i] = W4[t + 256 * i];
    }
    int n0 = blockIdx.x * 32;
    {   // stage h tile: 1024 float4 / 256 threads = 4 each (zero-fill tail)
        const float4* h4 = (const float4*)h;
        float4* hl4 = (float4*)hl;
        #pragma unroll
        for (int r = 0; r < 4; ++r) {
            int i = t + 256 * r;
            int n = i >> 5, q = i & 31;
            float4 v = {0.f, 0.f, 0.f, 0.f};
            if (n0 + n < N_NODES) v = h4[(size_t)(n0 + n) * 32 + q];
            hl4[n * 32 + q] = v;
        }
    }
    __syncthreads();
    int ng = t >> 5, cg = t & 31;
    const float4* hl4 = (const float4*)hl;
    const float4* Wl4 = (const float4*)Wl;
    float4 acc[4];
    #pragma unroll
    for (int i = 0; i < 4; ++i) acc[i] = {0.f, 0.f, 0.f, 0.f};
    for (int k4 = 0; k4 < 32; ++k4) {
        float4 a0 = hl4[(ng * 4 + 0) * 32 + k4];
        float4 a1 = hl4[(ng * 4 + 1) * 32 + k4];
        float4 a2 = hl4[(ng * 4 + 2) * 32 + k4];
        float4 a3 = hl4[(ng * 4 + 3) * 32 + k4];
        #pragma unroll
        for (int kk = 0; kk < 4; ++kk) {
            float4 w = Wl4[(k4 * 4 + kk) * 32 + cg];
            float c0 = ((const float*)&a0)[kk];
            float c1 = ((const float*)&a1)[kk];
            float c2 = ((const float*)&a2)[kk];
            float c3 = ((const float*)&a3)[kk];
            acc[0].x += c0 * w.x; acc[0].y += c0 * w.y; acc[0].z += c0 * w.z; acc[0].w += c0 * w.w;
            acc[1].x += c1 * w.x; acc[1].y += c1 * w.y; acc[1].z += c1 * w.z; acc[1].w += c1 * w.w;
            acc[2].x += c2 * w.x; acc[2].y += c2 * w.y; acc[2].z += c2 * w.z; acc[2].w += c2 * w.w;
            acc[3].x += c3 * w.x; acc[3].y += c3 * w.y; acc[3].z += c3 * w.z; acc[3].w += c3 * w.w;
        }
    }
    int hd = cg >> 3;            // head of this 4-channel group
    float a0v = al[cg * 4], a1v = al[cg * 4 + 1], a2v = al[cg * 4 + 2], a3v = al[cg * 4 + 3];
    float r0v = ar[cg * 4], r1v = ar[cg * 4 + 1], r2v = ar[cg * 4 + 2], r3v = ar[cg * 4 + 3];
    #pragma unroll
    for (int i = 0; i < 4; ++i) {
        int n = n0 + ng * 4 + i;
        if (n >= N_NODES) break;             // uniform across the 8-lane head group
        uint2 pk;
        pk.x = pack_bf2(acc[i].x, acc[i].y);
        pk.y = pack_bf2(acc[i].z, acc[i].w);
        *(uint2*)(featb + (size_t)n * 64 + cg * 2) = pk;
        float pl = acc[i].x * a0v + acc[i].y * a1v + acc[i].z * a2v + acc[i].w * a3v;
        float pr = acc[i].x * r0v + acc[i].y * r1v + acc[i].z * r2v + acc[i].w * r3v;
        #pragma unroll
        for (int off = 1; off < 8; off <<= 1) {
            pl += __shfl_xor(pl, off, 64);
            pr += __shfl_xor(pr, off, 64);
        }
        if ((t & 7) == 0) {
            el[n * 4 + hd] = pl;
            er[n * 4 + hd] = pr;
        }
    }
}

// Fused softmax + aggregation + ELU. One 64-lane wave per dst node.
// feat gather is bf16-packed: one uint per lane = channels (2*lane, 2*lane+1).
__global__ void gat_aggregate(const int* __restrict__ row_start, const int* __restrict__ csr_src,
                              const unsigned* __restrict__ featb, const float* __restrict__ el,
                              const float* __restrict__ er, float* __restrict__ hout) {
    int lane = threadIdx.x & 63;
    int d = blockIdx.x * 4 + (threadIdx.x >> 6);
    int beg = row_start[d], end = row_start[d + 1];
    int j = lane >> 2;           // edge slot 0..15
    int h = lane & 3;            // head (for ex phase)
    float er_h = er[d * 4 + h];
    int hc = lane >> 4;          // head of this lane's channel pair
    float accx = 0.f, accy = 0.f, dsum = 0.f;
    for (int base = beg; base < end; base += 16) {
        int idx = base + j;
        bool valid = idx < end;
        int s = csr_src[valid ? idx : beg];
        float ev = el[s * 4 + h] + er_h;
        ev = ev > 0.f ? ev : NEG_SLOPE * ev;
        float ex = valid ? __expf(ev) : 0.f;
        dsum += ex;
        int cnt = min(16, end - base);
        for (int jj = 0; jj < cnt; ++jj) {
            int   sj  = __shfl(s,  jj * 4, 64);
            float exj = __shfl(ex, jj * 4 + hc, 64);
            unsigned pv = (featb + (size_t)sj * 64)[lane];
            float fx = __uint_as_float(pv << 16);
            float fy = __uint_as_float(pv & 0xFFFF0000u);
            accx += fx * exj;
            accy += fy * exj;
        }
    }
    #pragma unroll
    for (int off = 4; off < 64; off <<= 1) dsum += __shfl_xor(dsum, off, 64);
    float dh = __shfl(dsum, hc, 64);
    float inv = 1.f / (dh + 1e-10f);
    float ox = accx * inv, oy = accy * inv;
    ox = ox > 0.f ? ox : expm1f(ox);
    oy = oy > 0.f ? oy : expm1f(oy);
    float2 o = {ox, oy};
    ((float2*)(hout + (size_t)d * 128))[lane] = o;
}

// ---------------- pooling / loss ----------------

__global__ void pool_kernel(const int* __restrict__ gid, const float* __restrict__ h,
                            unsigned* __restrict__ pkeys) {
    int t = threadIdx.x;
    int c = t & 127;
    int par = t >> 7;              // 0/1
    int n0 = blockIdx.x * POOL_CHUNK;
    float m = 0.f;
    int cur_g = -1;
    for (int n = n0 + par; n < n0 + POOL_CHUNK; n += 2) {
        int g = gid[n];
        if (g != cur_g) {
            if (cur_g >= 0) atomicMax(&pkeys[cur_g * 128 + c], fkey(m));
            cur_g = g;
            m = -3.0e38f;
        }
        m = fmaxf(m, h[(size_t)n * 128 + c]);
    }
    if (cur_g >= 0) atomicMax(&pkeys[cur_g * 128 + c], fkey(m));
}

__global__ void logits_kernel(const unsigned* __restrict__ pkeys, const float* __restrict__ w,
                              const float* __restrict__ bptr, float* __restrict__ logits) {
    int g = blockIdx.x, t = threadIdx.x;      // 64 blocks x 64 threads
    float sum = 0.f;
    for (int c = t; c < 128; c += 64) {
        unsigned k = pkeys[g * 128 + c];
        float v = (k == 0u) ? 0.f : kval(k);
        sum += v * w[c];
    }
    #pragma unroll
    for (int off = 32; off; off >>= 1) sum += __shfl_down(sum, off, 64);
    if (t == 0) logits[g] = sum + bptr[0];
}

__global__ void final_kernel(const float* __restrict__ logits, const float* __restrict__ y,
                             float* __restrict__ out) {
    int t = threadIdx.x;  // 64
    float l = logits[t];
    float term = fmaxf(l, 0.f) - l * y[t] + log1pf(expf(-fabsf(l)));
    float s = term;
    #pragma unroll
    for (int off = 32; off; off >>= 1) s += __shfl_down(s, off, 64);
    out[1 + t] = 1.f / (1.f + expf(-l));
    if (t == 0) out[0] = s * (1.f / 64.f);
}

extern "C" void kernel_launch(void* const* d_in, const int* in_sizes, int n_in,
                              void* d_out, int out_size, void* d_ws, size_t ws_size,
                              hipStream_t stream) {
    const int* word_ids  = (const int*)d_in[0];
    const int* esrc      = (const int*)d_in[1];
    const int* edst      = (const int*)d_in[2];
    const int* gid       = (const int*)d_in[3];
    const float* y_data  = (const float*)d_in[4];
    const float* emb     = (const float*)d_in[5];
    const float* W0      = (const float*)d_in[6];
    const float* al0     = (const float*)d_in[7];
    const float* ar0     = (const float*)d_in[8];
    const float* W1      = (const float*)d_in[9];
    const float* al1     = (const float*)d_in[10];
    const float* ar1     = (const float*)d_in[11];
    const float* out_w   = (const float*)d_in[12];
    const float* out_b   = (const float*)d_in[13];
    float* out = (float*)d_out;

    // workspace layout (float offsets); ~45 MB total
    float* ws = (float*)d_ws;
    unsigned* featb  = (unsigned*)ws;                // N*64 uints = 3,200,000
    float*    hbuf   = ws + 3200000;                 // N*128 = 6,400,000
    float*    el     = ws + 9600000;                 // 200,000
    float*    er     = ws + 9800000;                 // 200,000
    int*      row_st = (int*)(ws + 10000000);        // 50,001
    int*      deg    = (int*)(ws + 10051000);        // 50,000
    int*      cursor = (int*)(ws + 10101000);        // 50,000
    int*      csrsrc = (int*)(ws + 10151000);        // 800,000
    int*      partial= (int*)(ws + 10951000);        // 196
    int*      boff   = (int*)(ws + 10951200);        // 196
    unsigned* pkeys  = (unsigned*)(ws + 10951400);   // 8,192
    float*    logits = ws + 10959592;                // 64

    // CSR build (shared by both layers)
    hipMemsetAsync(deg, 0, (size_t)N_NODES * 4, stream);
    hist_kernel<<<3125, 256, 0, stream>>>(edst, deg);
    partial_kernel<<<SCAN_NB, 256, 0, stream>>>(deg, partial);
    boff_kernel<<<1, 256, 0, stream>>>(partial, boff);
    csr_offsets_kernel<<<SCAN_NB, 256, 0, stream>>>(deg, boff, row_st, cursor);
    scatter_kernel<<<3125, 256, 0, stream>>>(esrc, edst, cursor, csrsrc);

    gather_kernel<<<6250, 256, 0, stream>>>(word_ids, (const float4*)emb, (float4*)hbuf);

    auto layer = [&](const float* W, const float* al, const float* ar) {
        feat_kernel<<<FEAT_NB, 256, 0, stream>>>(hbuf, W, al, ar, featb, el, er);
        gat_aggregate<<<12500, 256, 0, stream>>>(row_st, csrsrc, featb, el, er, hbuf);
    };
    layer(W0, al0, ar0);
    layer(W1, al1, ar1);

    hipMemsetAsync(pkeys, 0, (size_t)N_GRAPHS * 128 * 4, stream);
    pool_kernel<<<POOL_NB, 256, 0, stream>>>(gid, hbuf, pkeys);
    logits_kernel<<<N_GRAPHS, 64, 0, stream>>>(pkeys, out_w, out_b, logits);
    final_kernel<<<1, 64, 0, stream>>>(logits, y_data, out);
}

// Round 9
// 383.167 us; speedup vs baseline: 1.7831x; 1.1072x over previous
//
#include <hip/hip_runtime.h>
#include <math.h>

#define N_NODES 50000
#define N_EDGES 800000
#define HEADS 4
#define N_GRAPHS 64
#define NEG_SLOPE 0.2f
#define SCAN_NB 196            // 196*256 = 50176 >= N_NODES
#define POOL_CHUNK 200
#define POOL_NB 250            // 250*200 = 50000 exactly
#define FEAT_NB 1563           // ceil(50000/32)

// monotone float<->uint key for atomicMax-based segment max (pooling).
__device__ __forceinline__ unsigned fkey(float f) {
    unsigned u = __float_as_uint(f);
    return (u & 0x80000000u) ? ~u : (u | 0x80000000u);
}
__device__ __forceinline__ float kval(unsigned k) {
    unsigned u = (k & 0x80000000u) ? (k & 0x7FFFFFFFu) : ~k;
    return __uint_as_float(u);
}

// f32 -> bf16 (RNE), two packed into one uint (lo = first channel)
__device__ __forceinline__ unsigned short f2bf(float f) {
    unsigned u = __float_as_uint(f);
    u += 0x7FFFu + ((u >> 16) & 1u);
    return (unsigned short)(u >> 16);
}
__device__ __forceinline__ unsigned pack_bf2(float a, float b) {
    return (unsigned)f2bf(a) | ((unsigned)f2bf(b) << 16);
}

// ---------------- CSR build (counting sort by dst) ----------------

__global__ void hist_kernel(const int* __restrict__ dst, int* __restrict__ deg) {
    int e = blockIdx.x * 256 + threadIdx.x;
    if (e < N_EDGES) atomicAdd(&deg[dst[e]], 1);
}

__global__ void partial_kernel(const int* __restrict__ deg, int* __restrict__ partial) {
    int t = threadIdx.x, b = blockIdx.x;
    int i = b * 256 + t;
    int v = (i < N_NODES) ? deg[i] : 0;
    #pragma unroll
    for (int off = 1; off < 64; off <<= 1) v += __shfl_xor(v, off, 64);
    __shared__ int wsum[4];
    if ((t & 63) == 0) wsum[t >> 6] = v;
    __syncthreads();
    if (t == 0) partial[b] = wsum[0] + wsum[1] + wsum[2] + wsum[3];
}

__global__ void boff_kernel(const int* __restrict__ partial, int* __restrict__ boff) {
    __shared__ int wsum[4];
    int t = threadIdx.x;          // 256
    int lane = t & 63, w = t >> 6;
    int v = (t < SCAN_NB) ? partial[t] : 0;
    int incl = v;
    #pragma unroll
    for (int off = 1; off < 64; off <<= 1) {
        int u = __shfl_up(incl, off, 64);
        if (lane >= off) incl += u;
    }
    if (lane == 63) wsum[w] = incl;
    __syncthreads();
    int woff = 0;
    #pragma unroll
    for (int k = 0; k < 4; ++k) if (k < w) woff += wsum[k];
    if (t < SCAN_NB) boff[t] = woff + incl - v;
}

__global__ void csr_offsets_kernel(const int* __restrict__ deg, const int* __restrict__ boff,
                                   int* __restrict__ row_start, int* __restrict__ cursor) {
    __shared__ int wsum[4];
    int t = threadIdx.x, b = blockIdx.x;
    int lane = t & 63, w = t >> 6;
    int i = b * 256 + t;
    int v = (i < N_NODES) ? deg[i] : 0;
    int incl = v;
    #pragma unroll
    for (int off = 1; off < 64; off <<= 1) {
        int u = __shfl_up(incl, off, 64);
        if (lane >= off) incl += u;
    }
    if (lane == 63) wsum[w] = incl;
    __syncthreads();
    int woff = boff[b];
    #pragma unroll
    for (int k = 0; k < 4; ++k) if (k < w) woff += wsum[k];
    int excl = woff + incl - v;
    if (i < N_NODES) { row_start[i] = excl; cursor[i] = excl; }
    else if (i == N_NODES) row_start[i] = excl;   // == N_EDGES
}

__global__ void scatter_kernel(const int* __restrict__ src, const int* __restrict__ dst,
                               int* __restrict__ cursor, int* __restrict__ csr_src) {
    int e = blockIdx.x * 256 + threadIdx.x;
    if (e < N_EDGES) {
        int p = atomicAdd(&cursor[dst[e]], 1);
        csr_src[p] = src[e];
    }
}

// ---------------- node pipeline ----------------

__global__ void gather_kernel(const int* __restrict__ wid, const float4* __restrict__ emb4,
                              float4* __restrict__ h4) {
    int i = blockIdx.x * 256 + threadIdx.x;   // N*32 threads exactly
    int n = i >> 5, q = i & 31;
    h4[i] = emb4[wid[n] * 32 + q];
}

// feat = h @ W (128x128). Register-tiled: 32 nodes/block, 256 threads,
// thread = (ng 0..7, cg 0..31) computes 4 nodes x 4 channels.
// el/er computed from f32 acc; feat stored as packed bf16 (2 ch / uint).
__global__ __launch_bounds__(256, 2)
void feat_kernel(const float* __restrict__ h, const float* __restrict__ W,
                 const float* __restrict__ al, const float* __restrict__ ar,
                 unsigned* __restrict__ featb, float* __restrict__ el,
                 float* __restrict__ er) {
    __shared__ float Wl[128 * 128];      // 64 KB
    __shared__ float hl[32 * 128];       // 16 KB
    int t = threadIdx.x;
    {   // stage W: 4096 float4 / 256 threads = 16 each
        const float4* W4 = (const float4*)W;
        float4* Wl4 = (float4*)Wl;
        #pragma unroll
        for (int i = 0; i < 16; ++i) Wl4[t + 256 * i] = W4[t + 256 * i];
    }
    int n0 = blockIdx.x * 32;
    {   // stage h tile: 1024 float4 / 256 threads = 4 each (zero-fill tail)
        const float4* h4 = (const float4*)h;
        float4* hl4 = (float4*)hl;
        #pragma unroll
        for (int r = 0; r < 4; ++r) {
            int i = t + 256 * r;
            int n = i >> 5, q = i & 31;
            float4 v = {0.f, 0.f, 0.f, 0.f};
            if (n0 + n < N_NODES) v = h4[(size_t)(n0 + n) * 32 + q];
            hl4[n * 32 + q] = v;
        }
    }
    __syncthreads();
    int ng = t >> 5, cg = t & 31;
    const float4* hl4 = (const float4*)hl;
    const float4* Wl4 = (const float4*)Wl;
    float4 acc[4];
    #pragma unroll
    for (int i = 0; i < 4; ++i) acc[i] = {0.f, 0.f, 0.f, 0.f};
    for (int k4 = 0; k4 < 32; ++k4) {
        float4 a0 = hl4[(ng * 4 + 0) * 32 + k4];
        float4 a1 = hl4[(ng * 4 + 1) * 32 + k4];
        float4 a2 = hl4[(ng * 4 + 2) * 32 + k4];
        float4 a3 = hl4[(ng * 4 + 3) * 32 + k4];
        #pragma unroll
        for (int kk = 0; kk < 4; ++kk) {
            float4 w = Wl4[(k4 * 4 + kk) * 32 + cg];
            float c0 = ((const float*)&a0)[kk];
            float c1 = ((const float*)&a1)[kk];
            float c2 = ((const float*)&a2)[kk];
            float c3 = ((const float*)&a3)[kk];
            acc[0].x += c0 * w.x; acc[0].y += c0 * w.y; acc[0].z += c0 * w.z; acc[0].w += c0 * w.w;
            acc[1].x += c1 * w.x; acc[1].y += c1 * w.y; acc[1].z += c1 * w.z; acc[1].w += c1 * w.w;
            acc[2].x += c2 * w.x; acc[2].y += c2 * w.y; acc[2].z += c2 * w.z; acc[2].w += c2 * w.w;
            acc[3].x += c3 * w.x; acc[3].y += c3 * w.y; acc[3].z += c3 * w.z; acc[3].w += c3 * w.w;
        }
    }
    int hd = cg >> 3;            // head of this 4-channel group
    float a0v = al[cg * 4], a1v = al[cg * 4 + 1], a2v = al[cg * 4 + 2], a3v = al[cg * 4 + 3];
    float r0v = ar[cg * 4], r1v = ar[cg * 4 + 1], r2v = ar[cg * 4 + 2], r3v = ar[cg * 4 + 3];
    #pragma unroll
    for (int i = 0; i < 4; ++i) {
        int n = n0 + ng * 4 + i;
        if (n >= N_NODES) break;             // uniform across the 8-lane head group
        uint2 pk;
        pk.x = pack_bf2(acc[i].x, acc[i].y);
        pk.y = pack_bf2(acc[i].z, acc[i].w);
        *(uint2*)(featb + (size_t)n * 64 + cg * 2) = pk;
        float pl = acc[i].x * a0v + acc[i].y * a1v + acc[i].z * a2v + acc[i].w * a3v;
        float pr = acc[i].x * r0v + acc[i].y * r1v + acc[i].z * r2v + acc[i].w * r3v;
        #pragma unroll
        for (int off = 1; off < 8; off <<= 1) {
            pl += __shfl_xor(pl, off, 64);
            pr += __shfl_xor(pr, off, 64);
        }
        if ((t & 7) == 0) {
            el[n * 4 + hd] = pl;
            er[n * 4 + hd] = pr;
        }
    }
}

// Fused softmax + aggregation + ELU. One 64-lane wave per dst node.
// NO cross-lane ops in the hot loop: each lane owns channels (2*lane,2*lane+1)
// of head hc=lane>>4 and recomputes ex(e,hc) itself (csr_src/el loads are
// wave-broadcast; the 16 lanes of a head duplicate identical exp work, which
// also makes dsum complete per-lane -> no reduction at the end).
// 4x unrolled: 4 independent s loads -> {4 el + 4 featb} loads -> FMAs.
__global__ void gat_aggregate(const int* __restrict__ row_start, const int* __restrict__ csr_src,
                              const unsigned* __restrict__ featb, const float* __restrict__ el,
                              const float* __restrict__ er, float* __restrict__ hout) {
    int lane = threadIdx.x & 63;
    int d = blockIdx.x * 4 + (threadIdx.x >> 6);
    int beg = row_start[d], end = row_start[d + 1];
    int hc = lane >> 4;          // this lane's head
    float er_h = er[d * 4 + hc];
    float accx = 0.f, accy = 0.f, dsum = 0.f;
    int e = beg;
    for (; e + 4 <= end; e += 4) {
        int s0 = csr_src[e + 0];
        int s1 = csr_src[e + 1];
        int s2 = csr_src[e + 2];
        int s3 = csr_src[e + 3];
        float l0 = el[s0 * 4 + hc];
        float l1 = el[s1 * 4 + hc];
        float l2 = el[s2 * 4 + hc];
        float l3 = el[s3 * 4 + hc];
        unsigned p0 = featb[(size_t)s0 * 64 + lane];
        unsigned p1 = featb[(size_t)s1 * 64 + lane];
        unsigned p2 = featb[(size_t)s2 * 64 + lane];
        unsigned p3 = featb[(size_t)s3 * 64 + lane];
        float v0 = l0 + er_h; v0 = v0 > 0.f ? v0 : NEG_SLOPE * v0;
        float v1 = l1 + er_h; v1 = v1 > 0.f ? v1 : NEG_SLOPE * v1;
        float v2 = l2 + er_h; v2 = v2 > 0.f ? v2 : NEG_SLOPE * v2;
        float v3 = l3 + er_h; v3 = v3 > 0.f ? v3 : NEG_SLOPE * v3;
        float x0 = __expf(v0), x1 = __expf(v1), x2 = __expf(v2), x3 = __expf(v3);
        dsum += (x0 + x1) + (x2 + x3);
        accx += __uint_as_float(p0 << 16) * x0;
        accy += __uint_as_float(p0 & 0xFFFF0000u) * x0;
        accx += __uint_as_float(p1 << 16) * x1;
        accy += __uint_as_float(p1 & 0xFFFF0000u) * x1;
        accx += __uint_as_float(p2 << 16) * x2;
        accy += __uint_as_float(p2 & 0xFFFF0000u) * x2;
        accx += __uint_as_float(p3 << 16) * x3;
        accy += __uint_as_float(p3 & 0xFFFF0000u) * x3;
    }
    for (; e < end; ++e) {
        int s = csr_src[e];
        float lv = el[s * 4 + hc];
        unsigned pv = featb[(size_t)s * 64 + lane];
        float v = lv + er_h; v = v > 0.f ? v : NEG_SLOPE * v;
        float x = __expf(v);
        dsum += x;
        accx += __uint_as_float(pv << 16) * x;
        accy += __uint_as_float(pv & 0xFFFF0000u) * x;
    }
    float inv = 1.f / (dsum + 1e-10f);
    float ox = accx * inv, oy = accy * inv;
    ox = ox > 0.f ? ox : expm1f(ox);
    oy = oy > 0.f ? oy : expm1f(oy);
    float2 o = {ox, oy};
    ((float2*)(hout + (size_t)d * 128))[lane] = o;
}

// ---------------- pooling / loss ----------------

__global__ void pool_kernel(const int* __restrict__ gid, const float* __restrict__ h,
                            unsigned* __restrict__ pkeys) {
    int t = threadIdx.x;
    int c = t & 127;
    int par = t >> 7;              // 0/1
    int n0 = blockIdx.x * POOL_CHUNK;
    float m = 0.f;
    int cur_g = -1;
    for (int n = n0 + par; n < n0 + POOL_CHUNK; n += 2) {
        int g = gid[n];
        if (g != cur_g) {
            if (cur_g >= 0) atomicMax(&pkeys[cur_g * 128 + c], fkey(m));
            cur_g = g;
            m = -3.0e38f;
        }
        m = fmaxf(m, h[(size_t)n * 128 + c]);
    }
    if (cur_g >= 0) atomicMax(&pkeys[cur_g * 128 + c], fkey(m));
}

__global__ void logits_kernel(const unsigned* __restrict__ pkeys, const float* __restrict__ w,
                              const float* __restrict__ bptr, float* __restrict__ logits) {
    int g = blockIdx.x, t = threadIdx.x;      // 64 blocks x 64 threads
    float sum = 0.f;
    for (int c = t; c < 128; c += 64) {
        unsigned k = pkeys[g * 128 + c];
        float v = (k == 0u) ? 0.f : kval(k);
        sum += v * w[c];
    }
    #pragma unroll
    for (int off = 32; off; off >>= 1) sum += __shfl_down(sum, off, 64);
    if (t == 0) logits[g] = sum + bptr[0];
}

__global__ void final_kernel(const float* __restrict__ logits, const float* __restrict__ y,
                             float* __restrict__ out) {
    int t = threadIdx.x;  // 64
    float l = logits[t];
    float term = fmaxf(l, 0.f) - l * y[t] + log1pf(expf(-fabsf(l)));
    float s = term;
    #pragma unroll
    for (int off = 32; off; off >>= 1) s += __shfl_down(s, off, 64);
    out[1 + t] = 1.f / (1.f + expf(-l));
    if (t == 0) out[0] = s * (1.f / 64.f);
}

extern "C" void kernel_launch(void* const* d_in, const int* in_sizes, int n_in,
                              void* d_out, int out_size, void* d_ws, size_t ws_size,
                              hipStream_t stream) {
    const int* word_ids  = (const int*)d_in[0];
    const int* esrc      = (const int*)d_in[1];
    const int* edst      = (const int*)d_in[2];
    const int* gid       = (const int*)d_in[3];
    const float* y_data  = (const float*)d_in[4];
    const float* emb     = (const float*)d_in[5];
    const float* W0      = (const float*)d_in[6];
    const float* al0     = (const float*)d_in[7];
    const float* ar0     = (const float*)d_in[8];
    const float* W1      = (const float*)d_in[9];
    const float* al1     = (const float*)d_in[10];
    const float* ar1     = (const float*)d_in[11];
    const float* out_w   = (const float*)d_in[12];
    const float* out_b   = (const float*)d_in[13];
    float* out = (float*)d_out;

    // workspace layout (float offsets); ~45 MB total
    float* ws = (float*)d_ws;
    unsigned* featb  = (unsigned*)ws;                // N*64 uints = 3,200,000
    float*    hbuf   = ws + 3200000;                 // N*128 = 6,400,000
    float*    el     = ws + 9600000;                 // 200,000
    float*    er     = ws + 9800000;                 // 200,000
    int*      row_st = (int*)(ws + 10000000);        // 50,001
    int*      deg    = (int*)(ws + 10051000);        // 50,000
    int*      cursor = (int*)(ws + 10101000);        // 50,000
    int*      csrsrc = (int*)(ws + 10151000);        // 800,000
    int*      partial= (int*)(ws + 10951000);        // 196
    int*      boff   = (int*)(ws + 10951200);        // 196
    unsigned* pkeys  = (unsigned*)(ws + 10951400);   // 8,192
    float*    logits = ws + 10959592;                // 64

    // CSR build (shared by both layers)
    hipMemsetAsync(deg, 0, (size_t)N_NODES * 4, stream);
    hist_kernel<<<3125, 256, 0, stream>>>(edst, deg);
    partial_kernel<<<SCAN_NB, 256, 0, stream>>>(deg, partial);
    boff_kernel<<<1, 256, 0, stream>>>(partial, boff);
    csr_offsets_kernel<<<SCAN_NB, 256, 0, stream>>>(deg, boff, row_st, cursor);
    scatter_kernel<<<3125, 256, 0, stream>>>(esrc, edst, cursor, csrsrc);

    gather_kernel<<<6250, 256, 0, stream>>>(word_ids, (const float4*)emb, (float4*)hbuf);

    auto layer = [&](const float* W, const float* al, const float* ar) {
        feat_kernel<<<FEAT_NB, 256, 0, stream>>>(hbuf, W, al, ar, featb, el, er);
        gat_aggregate<<<12500, 256, 0, stream>>>(row_st, csrsrc, featb, el, er, hbuf);
    };
    layer(W0, al0, ar0);
    layer(W1, al1, ar1);

    hipMemsetAsync(pkeys, 0, (size_t)N_GRAPHS * 128 * 4, stream);
    pool_kernel<<<POOL_NB, 256, 0, stream>>>(gid, hbuf, pkeys);
    logits_kernel<<<N_GRAPHS, 64, 0, stream>>>(pkeys, out_w, out_b, logits);
    final_kernel<<<1, 64, 0, stream>>>(logits, y_data, out);
}

// Round 10
// 339.294 us; speedup vs baseline: 2.0136x; 1.1293x over previous
//
#include <hip/hip_runtime.h>
#include <math.h>

#define N_NODES 50000
#define N_EDGES 800000
#define HEADS 4
#define N_GRAPHS 64
#define NEG_SLOPE 0.2f
#define SCAN_NB 196            // 196*256 = 50176 >= N_NODES
#define POOL_CHUNK 200
#define POOL_NB 250            // 250*200 = 50000 exactly
#define FEAT_NB 1563           // ceil(50000/32)
#define EDGE_Q 200000          // N_EDGES/4: 4 edges per thread
#define EDGE_NB 782            // ceil(200000/256)

// monotone float<->uint key for atomicMax-based segment max (pooling).
__device__ __forceinline__ unsigned fkey(float f) {
    unsigned u = __float_as_uint(f);
    return (u & 0x80000000u) ? ~u : (u | 0x80000000u);
}
__device__ __forceinline__ float kval(unsigned k) {
    unsigned u = (k & 0x80000000u) ? (k & 0x7FFFFFFFu) : ~k;
    return __uint_as_float(u);
}

// f32 -> bf16 (RNE), two packed into one uint (lo = first channel)
__device__ __forceinline__ unsigned short f2bf(float f) {
    unsigned u = __float_as_uint(f);
    u += 0x7FFFu + ((u >> 16) & 1u);
    return (unsigned short)(u >> 16);
}
__device__ __forceinline__ unsigned pack_bf2(float a, float b) {
    return (unsigned)f2bf(a) | ((unsigned)f2bf(b) << 16);
}

// ---------------- CSR build (counting sort by dst, rank-based) ----------------

// deg histogram + per-edge rank within its dst segment. 4 edges/thread (ILP).
__global__ void hist_kernel(const int* __restrict__ dst, int* __restrict__ deg,
                            int* __restrict__ rank) {
    int i = blockIdx.x * 256 + threadIdx.x;
    if (i >= EDGE_Q) return;
    int e0 = i, e1 = i + EDGE_Q, e2 = i + 2 * EDGE_Q, e3 = i + 3 * EDGE_Q;
    int d0 = dst[e0], d1 = dst[e1], d2 = dst[e2], d3 = dst[e3];
    int r0 = atomicAdd(&deg[d0], 1);
    int r1 = atomicAdd(&deg[d1], 1);
    int r2 = atomicAdd(&deg[d2], 1);
    int r3 = atomicAdd(&deg[d3], 1);
    rank[e0] = r0; rank[e1] = r1; rank[e2] = r2; rank[e3] = r3;
}

// per-block sums of deg (256 elements/block)
__global__ void partial_kernel(const int* __restrict__ deg, int* __restrict__ partial) {
    int t = threadIdx.x, b = blockIdx.x;
    int i = b * 256 + t;
    int v = (i < N_NODES) ? deg[i] : 0;
    #pragma unroll
    for (int off = 1; off < 64; off <<= 1) v += __shfl_xor(v, off, 64);
    __shared__ int wsum[4];
    if ((t & 63) == 0) wsum[t >> 6] = v;
    __syncthreads();
    if (t == 0) partial[b] = wsum[0] + wsum[1] + wsum[2] + wsum[3];
}

// block-level exclusive scan of deg -> row_start; block offset computed by
// redundantly scanning partial[SCAN_NB] inside every block (cheap, -1 dispatch).
__global__ void csr_offsets_kernel(const int* __restrict__ deg, const int* __restrict__ partial,
                                   int* __restrict__ row_start) {
    __shared__ int sb[SCAN_NB];
    __shared__ int wsumA[4];
    __shared__ int wsumB[4];
    int t = threadIdx.x, b = blockIdx.x;
    int lane = t & 63, w = t >> 6;
    {   // exclusive scan of partial -> sb
        int v = (t < SCAN_NB) ? partial[t] : 0;
        int incl = v;
        #pragma unroll
        for (int off = 1; off < 64; off <<= 1) {
            int u = __shfl_up(incl, off, 64);
            if (lane >= off) incl += u;
        }
        if (lane == 63) wsumA[w] = incl;
        __syncthreads();
        int woff = 0;
        #pragma unroll
        for (int k = 0; k < 4; ++k) if (k < w) woff += wsumA[k];
        if (t < SCAN_NB) sb[t] = woff + incl - v;
        __syncthreads();
    }
    int i = b * 256 + t;
    int v = (i < N_NODES) ? deg[i] : 0;
    int incl = v;
    #pragma unroll
    for (int off = 1; off < 64; off <<= 1) {
        int u = __shfl_up(incl, off, 64);
        if (lane >= off) incl += u;
    }
    if (lane == 63) wsumB[w] = incl;
    __syncthreads();
    int woff = sb[b];
    #pragma unroll
    for (int k = 0; k < 4; ++k) if (k < w) woff += wsumB[k];
    int excl = woff + incl - v;
    if (i < N_NODES) row_start[i] = excl;
    else if (i == N_NODES) row_start[i] = excl;   // == N_EDGES
}

// atomic-free scatter: pos = row_start[dst] + rank. 4 edges/thread (ILP).
__global__ void scatter_kernel(const int* __restrict__ src, const int* __restrict__ dst,
                               const int* __restrict__ rank, const int* __restrict__ row_start,
                               int* __restrict__ csr_src) {
    int i = blockIdx.x * 256 + threadIdx.x;
    if (i >= EDGE_Q) return;
    int e0 = i, e1 = i + EDGE_Q, e2 = i + 2 * EDGE_Q, e3 = i + 3 * EDGE_Q;
    int d0 = dst[e0], d1 = dst[e1], d2 = dst[e2], d3 = dst[e3];
    int k0 = rank[e0], k1 = rank[e1], k2 = rank[e2], k3 = rank[e3];
    int s0 = src[e0], s1 = src[e1], s2 = src[e2], s3 = src[e3];
    int p0 = row_start[d0] + k0;
    int p1 = row_start[d1] + k1;
    int p2 = row_start[d2] + k2;
    int p3 = row_start[d3] + k3;
    csr_src[p0] = s0;
    csr_src[p1] = s1;
    csr_src[p2] = s2;
    csr_src[p3] = s3;
}

// ---------------- node pipeline ----------------

// feat = h @ W (128x128). Register-tiled: 32 nodes/block, 256 threads,
// thread = (ng 0..7, cg 0..31) computes 4 nodes x 4 channels.
// Layer 0: wid != nullptr -> rows gathered from emb[wid[n]] during staging
// (fuses the old gather_kernel). el/er from f32 acc; feat stored packed bf16.
__global__ __launch_bounds__(256, 2)
void feat_kernel(const float* __restrict__ h, const int* __restrict__ wid,
                 const float* __restrict__ W,
                 const float* __restrict__ al, const float* __restrict__ ar,
                 unsigned* __restrict__ featb, float* __restrict__ el,
                 float* __restrict__ er) {
    __shared__ float Wl[128 * 128];      // 64 KB
    __shared__ float hl[32 * 128];       // 16 KB
    int t = threadIdx.x;
    {   // stage W: 4096 float4 / 256 threads = 16 each
        const float4* W4 = (const float4*)W;
        float4* Wl4 = (float4*)Wl;
        #pragma unroll
        for (int i = 0; i < 16; ++i) Wl4[t + 256 * i] = W4[t + 256 * i];
    }
    int n0 = blockIdx.x * 32;
    {   // stage h tile: 1024 float4 / 256 threads = 4 each (zero-fill tail)
        const float4* h4 = (const float4*)h;
        float4* hl4 = (float4*)hl;
        #pragma unroll
        for (int r = 0; r < 4; ++r) {
            int i = t + 256 * r;
            int n = i >> 5, q = i & 31;
            float4 v = {0.f, 0.f, 0.f, 0.f};
            int gn = n0 + n;
            if (gn < N_NODES) {
                int row = wid ? wid[gn] : gn;
                v = h4[(size_t)row * 32 + q];
            }
            hl4[n * 32 + q] = v;
        }
    }
    __syncthreads();
    int ng = t >> 5, cg = t & 31;
    const float4* hl4 = (const float4*)hl;
    const float4* Wl4 = (const float4*)Wl;
    float4 acc[4];
    #pragma unroll
    for (int i = 0; i < 4; ++i) acc[i] = {0.f, 0.f, 0.f, 0.f};
    for (int k4 = 0; k4 < 32; ++k4) {
        float4 a0 = hl4[(ng * 4 + 0) * 32 + k4];
        float4 a1 = hl4[(ng * 4 + 1) * 32 + k4];
        float4 a2 = hl4[(ng * 4 + 2) * 32 + k4];
        float4 a3 = hl4[(ng * 4 + 3) * 32 + k4];
        #pragma unroll
        for (int kk = 0; kk < 4; ++kk) {
            float4 w = Wl4[(k4 * 4 + kk) * 32 + cg];
            float c0 = ((const float*)&a0)[kk];
            float c1 = ((const float*)&a1)[kk];
            float c2 = ((const float*)&a2)[kk];
            float c3 = ((const float*)&a3)[kk];
            acc[0].x += c0 * w.x; acc[0].y += c0 * w.y; acc[0].z += c0 * w.z; acc[0].w += c0 * w.w;
            acc[1].x += c1 * w.x; acc[1].y += c1 * w.y; acc[1].z += c1 * w.z; acc[1].w += c1 * w.w;
            acc[2].x += c2 * w.x; acc[2].y += c2 * w.y; acc[2].z += c2 * w.z; acc[2].w += c2 * w.w;
            acc[3].x += c3 * w.x; acc[3].y += c3 * w.y; acc[3].z += c3 * w.z; acc[3].w += c3 * w.w;
        }
    }
    int hd = cg >> 3;            // head of this 4-channel group
    float a0v = al[cg * 4], a1v = al[cg * 4 + 1], a2v = al[cg * 4 + 2], a3v = al[cg * 4 + 3];
    float r0v = ar[cg * 4], r1v = ar[cg * 4 + 1], r2v = ar[cg * 4 + 2], r3v = ar[cg * 4 + 3];
    #pragma unroll
    for (int i = 0; i < 4; ++i) {
        int n = n0 + ng * 4 + i;
        if (n >= N_NODES) break;             // uniform across the 8-lane head group
        uint2 pk;
        pk.x = pack_bf2(acc[i].x, acc[i].y);
        pk.y = pack_bf2(acc[i].z, acc[i].w);
        *(uint2*)(featb + (size_t)n * 64 + cg * 2) = pk;
        float pl = acc[i].x * a0v + acc[i].y * a1v + acc[i].z * a2v + acc[i].w * a3v;
        float pr = acc[i].x * r0v + acc[i].y * r1v + acc[i].z * r2v + acc[i].w * r3v;
        #pragma unroll
        for (int off = 1; off < 8; off <<= 1) {
            pl += __shfl_xor(pl, off, 64);
            pr += __shfl_xor(pr, off, 64);
        }
        if ((t & 7) == 0) {
            el[n * 4 + hd] = pl;
            er[n * 4 + hd] = pr;
        }
    }
}

// Fused softmax + aggregation + ELU. One 64-lane wave per dst node.
// No cross-lane ops in the hot loop (each lane recomputes ex for its head).
__global__ void gat_aggregate(const int* __restrict__ row_start, const int* __restrict__ csr_src,
                              const unsigned* __restrict__ featb, const float* __restrict__ el,
                              const float* __restrict__ er, float* __restrict__ hout) {
    int lane = threadIdx.x & 63;
    int d = blockIdx.x * 4 + (threadIdx.x >> 6);
    int beg = row_start[d], end = row_start[d + 1];
    int hc = lane >> 4;          // this lane's head
    float er_h = er[d * 4 + hc];
    float accx = 0.f, accy = 0.f, dsum = 0.f;
    int e = beg;
    for (; e + 4 <= end; e += 4) {
        int s0 = csr_src[e + 0];
        int s1 = csr_src[e + 1];
        int s2 = csr_src[e + 2];
        int s3 = csr_src[e + 3];
        float l0 = el[s0 * 4 + hc];
        float l1 = el[s1 * 4 + hc];
        float l2 = el[s2 * 4 + hc];
        float l3 = el[s3 * 4 + hc];
        unsigned p0 = featb[(size_t)s0 * 64 + lane];
        unsigned p1 = featb[(size_t)s1 * 64 + lane];
        unsigned p2 = featb[(size_t)s2 * 64 + lane];
        unsigned p3 = featb[(size_t)s3 * 64 + lane];
        float v0 = l0 + er_h; v0 = v0 > 0.f ? v0 : NEG_SLOPE * v0;
        float v1 = l1 + er_h; v1 = v1 > 0.f ? v1 : NEG_SLOPE * v1;
        float v2 = l2 + er_h; v2 = v2 > 0.f ? v2 : NEG_SLOPE * v2;
        float v3 = l3 + er_h; v3 = v3 > 0.f ? v3 : NEG_SLOPE * v3;
        float x0 = __expf(v0), x1 = __expf(v1), x2 = __expf(v2), x3 = __expf(v3);
        dsum += (x0 + x1) + (x2 + x3);
        accx += __uint_as_float(p0 << 16) * x0;
        accy += __uint_as_float(p0 & 0xFFFF0000u) * x0;
        accx += __uint_as_float(p1 << 16) * x1;
        accy += __uint_as_float(p1 & 0xFFFF0000u) * x1;
        accx += __uint_as_float(p2 << 16) * x2;
        accy += __uint_as_float(p2 & 0xFFFF0000u) * x2;
        accx += __uint_as_float(p3 << 16) * x3;
        accy += __uint_as_float(p3 & 0xFFFF0000u) * x3;
    }
    for (; e < end; ++e) {
        int s = csr_src[e];
        float lv = el[s * 4 + hc];
        unsigned pv = featb[(size_t)s * 64 + lane];
        float v = lv + er_h; v = v > 0.f ? v : NEG_SLOPE * v;
        float x = __expf(v);
        dsum += x;
        accx += __uint_as_float(pv << 16) * x;
        accy += __uint_as_float(pv & 0xFFFF0000u) * x;
    }
    float inv = 1.f / (dsum + 1e-10f);
    float ox = accx * inv, oy = accy * inv;
    ox = ox > 0.f ? ox : expm1f(ox);
    oy = oy > 0.f ? oy : expm1f(oy);
    float2 o = {ox, oy};
    ((float2*)(hout + (size_t)d * 128))[lane] = o;
}

// ---------------- pooling / loss ----------------

__global__ void pool_kernel(const int* __restrict__ gid, const float* __restrict__ h,
                            unsigned* __restrict__ pkeys) {
    int t = threadIdx.x;
    int c = t & 127;
    int par = t >> 7;              // 0/1
    int n0 = blockIdx.x * POOL_CHUNK;
    float m = 0.f;
    int cur_g = -1;
    for (int n = n0 + par; n < n0 + POOL_CHUNK; n += 2) {
        int g = gid[n];
        if (g != cur_g) {
            if (cur_g >= 0) atomicMax(&pkeys[cur_g * 128 + c], fkey(m));
            cur_g = g;
            m = -3.0e38f;
        }
        m = fmaxf(m, h[(size_t)n * 128 + c]);
    }
    if (cur_g >= 0) atomicMax(&pkeys[cur_g * 128 + c], fkey(m));
}

__global__ void logits_kernel(const unsigned* __restrict__ pkeys, const float* __restrict__ w,
                              const float* __restrict__ bptr, float* __restrict__ logits) {
    int g = blockIdx.x, t = threadIdx.x;      // 64 blocks x 64 threads
    float sum = 0.f;
    for (int c = t; c < 128; c += 64) {
        unsigned k = pkeys[g * 128 + c];
        float v = (k == 0u) ? 0.f : kval(k);
        sum += v * w[c];
    }
    #pragma unroll
    for (int off = 32; off; off >>= 1) sum += __shfl_down(sum, off, 64);
    if (t == 0) logits[g] = sum + bptr[0];
}

__global__ void final_kernel(const float* __restrict__ logits, const float* __restrict__ y,
                             float* __restrict__ out) {
    int t = threadIdx.x;  // 64
    float l = logits[t];
    float term = fmaxf(l, 0.f) - l * y[t] + log1pf(expf(-fabsf(l)));
    float s = term;
    #pragma unroll
    for (int off = 32; off; off >>= 1) s += __shfl_down(s, off, 64);
    out[1 + t] = 1.f / (1.f + expf(-l));
    if (t == 0) out[0] = s * (1.f / 64.f);
}

extern "C" void kernel_launch(void* const* d_in, const int* in_sizes, int n_in,
                              void* d_out, int out_size, void* d_ws, size_t ws_size,
                              hipStream_t stream) {
    const int* word_ids  = (const int*)d_in[0];
    const int* esrc      = (const int*)d_in[1];
    const int* edst      = (const int*)d_in[2];
    const int* gid       = (const int*)d_in[3];
    const float* y_data  = (const float*)d_in[4];
    const float* emb     = (const float*)d_in[5];
    const float* W0      = (const float*)d_in[6];
    const float* al0     = (const float*)d_in[7];
    const float* ar0     = (const float*)d_in[8];
    const float* W1      = (const float*)d_in[9];
    const float* al1     = (const float*)d_in[10];
    const float* ar1     = (const float*)d_in[11];
    const float* out_w   = (const float*)d_in[12];
    const float* out_b   = (const float*)d_in[13];
    float* out = (float*)d_out;

    // workspace layout (float offsets); ~47 MB total
    float* ws = (float*)d_ws;
    unsigned* featb  = (unsigned*)ws;                // N*64 uints = 3,200,000
    float*    hbuf   = ws + 3200000;                 // N*128 = 6,400,000
    float*    el     = ws + 9600000;                 // 200,000
    float*    er     = ws + 9800000;                 // 200,000
    int*      row_st = (int*)(ws + 10000000);        // 50,001
    int*      deg    = (int*)(ws + 10051000);        // 50,000
    int*      rank   = (int*)(ws + 10101000);        // 800,000
    int*      csrsrc = (int*)(ws + 10901000);        // 800,000
    int*      partial= (int*)(ws + 11701000);        // 196
    unsigned* pkeys  = (unsigned*)(ws + 11701400);   // 8,192
    float*    logits = ws + 11709592;                // 64

    // CSR build (shared by both layers)
    hipMemsetAsync(deg, 0, (size_t)N_NODES * 4, stream);
    hist_kernel<<<EDGE_NB, 256, 0, stream>>>(edst, deg, rank);
    partial_kernel<<<SCAN_NB, 256, 0, stream>>>(deg, partial);
    csr_offsets_kernel<<<SCAN_NB, 256, 0, stream>>>(deg, partial, row_st);
    scatter_kernel<<<EDGE_NB, 256, 0, stream>>>(esrc, edst, rank, row_st, csrsrc);

    // layer 0 (gather fused into feat staging), then layer 1
    feat_kernel<<<FEAT_NB, 256, 0, stream>>>(emb, word_ids, W0, al0, ar0, featb, el, er);
    gat_aggregate<<<12500, 256, 0, stream>>>(row_st, csrsrc, featb, el, er, hbuf);
    feat_kernel<<<FEAT_NB, 256, 0, stream>>>(hbuf, nullptr, W1, al1, ar1, featb, el, er);
    gat_aggregate<<<12500, 256, 0, stream>>>(row_st, csrsrc, featb, el, er, hbuf);

    hipMemsetAsync(pkeys, 0, (size_t)N_GRAPHS * 128 * 4, stream);
    pool_kernel<<<POOL_NB, 256, 0, stream>>>(gid, hbuf, pkeys);
    logits_kernel<<<N_GRAPHS, 64, 0, stream>>>(pkeys, out_w, out_b, logits);
    final_kernel<<<1, 64, 0, stream>>>(logits, y_data, out);
}